// Round 16
// baseline (2619.632 us; speedup 1.0000x reference)
//
#include <hip/hip_runtime.h>
#include <cstdint>
#include <cstddef>

#define S_LEN 512
#define HDIM  128
#define G4    512
#define BATCH 256
#define NLAYER 10
#define ROWS  16
#define NBLK  (BATCH / ROWS)  // 16
#define RING  10
#define PPS   20              // pp col stride in floats (80B: 16B-aligned, (5c)%8 bank spread)

typedef float f32x4 __attribute__((ext_vector_type(4)));
typedef short short8 __attribute__((ext_vector_type(8)));
typedef _Float16 h16x4 __attribute__((ext_vector_type(4)));
typedef _Float16 h16x8 __attribute__((ext_vector_type(8)));

__device__ __forceinline__ float fsig(float x) {
  return __builtin_amdgcn_rcpf(1.0f + __expf(-x));
}
__device__ __forceinline__ float ftanh(float x) {
  return fmaf(2.0f, __builtin_amdgcn_rcpf(1.0f + __expf(-2.0f * x)), -1.0f);
}
__device__ __forceinline__ unsigned short bf16_rne(float x) {
  unsigned int u = __float_as_uint(x);
  unsigned int r = (u + 0x7fffu + ((u >> 16) & 1u)) >> 16;
  return (unsigned short)r;
}
__device__ __forceinline__ float bf16_to_f(unsigned short h) {
  return __uint_as_float(((unsigned int)h) << 16);
}

// XGS layout per chunk slot (slot = c % RING), fp16:
//   elem at ((tt*16 + bi)*16 + w)*512 + ln*8 + ct*4 + j
//   = XG[b = bi*16 + (ln>>4)*4 + j][t = t0+tt][col = w*32 + ct*16 + (ln&15)]

// ---------------------------------------------------------------------------
__global__ void split_w(const float* __restrict__ W, unsigned short* __restrict__ hi,
                        unsigned short* __restrict__ lo, int n)
{
  int i = blockIdx.x * 256 + threadIdx.x;
  if (i < n) {
    float x = W[i];
    unsigned short h = bf16_rne(x);
    hi[i] = h;
    lo[i] = bf16_rne(x - bf16_to_f(h));
  }
}

// Pad w_ih0 [512][27] -> split bf16 [512][32] (zeros in k=27..31).
__global__ void w0_prep(const float* __restrict__ W, unsigned short* __restrict__ hi,
                        unsigned short* __restrict__ lo)
{
  int i = blockIdx.x * 256 + threadIdx.x;
  if (i >= 512 * 32) return;
  int col = i >> 5, k = i & 31;
  float v = (k < 27) ? W[col * 27 + k] : 0.f;
  unsigned short h = bf16_rne(v);
  hi[i] = h;
  lo[i] = bf16_rne(v - bf16_to_f(h));
}

// ---------------------------------------------------------------------------
// Pre-arrange split Whh into MFMA B-fragment-linear order (verified round 7).
// ---------------------------------------------------------------------------
__global__ __launch_bounds__(256)
void whh_prep(const float* __restrict__ Whh, unsigned short* __restrict__ WF)
{
  int idx = blockIdx.x * 256 + threadIdx.x;
  if (idx >= NLAYER * 16 * 16 * 64) return;
  int ln = idx & 63;
  int f  = (idx >> 6) & 15;
  int w  = (idx >> 10) & 15;
  int l  = idx >> 14;
  int ct = f >> 3, ks = (f >> 1) & 3, hl = f & 1;
  int col = w * 32 + ct * 16 + (ln & 15);
  int k0  = ks * 32 + (ln >> 4) * 8;
  const float* src = Whh + ((size_t)l * G4 + col) * HDIM + k0;
  unsigned short out[8];
  #pragma unroll
  for (int j = 0; j < 8; ++j) {
    float x = src[j];
    unsigned short h = bf16_rne(x);
    out[j] = hl ? bf16_rne(x - bf16_to_f(h)) : h;
  }
  *(short8*)&WF[(size_t)idx * 8] = *(short8*)out;
}

// ---------------------------------------------------------------------------
// Unified input-projection GEMM (layers 0..9) — round-15 verbatim (verified).
// ---------------------------------------------------------------------------
__global__ __launch_bounds__(1024, 4)
void gemm_st(const float* __restrict__ x,
             const float* __restrict__ H0, const float* __restrict__ H1,
             const unsigned short* __restrict__ W0hi, const unsigned short* __restrict__ W0lo,
             const unsigned short* __restrict__ WhiAll, const unsigned short* __restrict__ WloAll,
             const float* __restrict__ bihAll, const float* __restrict__ bhhAll,
             _Float16* __restrict__ XGring, int tchShift, int s, int lmin)
{
  __shared__ unsigned short Ahi[4 * 16 * HDIM];
  __shared__ unsigned short Alo[4 * 16 * HDIM];
  __shared__ unsigned short Bhi[64 * HDIM];
  __shared__ unsigned short Blo[64 * HDIM];

  const int l  = lmin + blockIdx.z;
  const int c  = s - l;
  const int bi = blockIdx.x;
  const int tg = blockIdx.y;
  const int tid = threadIdx.x;
  const int t0 = c << tchShift;
  const size_t slotF = ((size_t)BATCH * G4) << tchShift;
  _Float16* __restrict__ XG = XGring + (size_t)(c % RING) * slotF;
  const float* bih = bihAll + l * G4;
  const float* bhh = bhhAll + l * G4;

  {
    int row = tid >> 4;
    int tw = row >> 4, rr = row & 15;
    int ks16 = tid & 15;
    int b = bi * 16 + rr;
    int t = t0 + tg * 4 + tw;
    if (l == 0) {
      if (ks16 < 4) {
        int kg = ks16 * 8;
        const float* ap = &x[((size_t)b * S_LEN + t) * 27];
        unsigned short h8[8], l8v[8];
        #pragma unroll
        for (int j = 0; j < 8; ++j) {
          int k = kg + j;
          float v = (k < 27) ? ap[k] : 0.f;
          unsigned short hh = bf16_rne(v);
          h8[j] = hh;
          l8v[j] = bf16_rne(v - bf16_to_f(hh));
        }
        int byA = tw * 4096 + ((rr * 256 + kg * 2) ^ ((rr & 7) << 4));
        *(short8*)((char*)Ahi + byA) = *(short8*)h8;
        *(short8*)((char*)Alo + byA) = *(short8*)l8v;
      }
    } else {
      int kg = ks16 * 8;
      const float* Asrc = ((l - 1) & 1) ? H1 : H0;
      const float* ap = &Asrc[((size_t)b * S_LEN + t) * HDIM + kg];
      float4 v0 = *(const float4*)ap;
      float4 v1 = *(const float4*)(ap + 4);
      float xs[8] = {v0.x, v0.y, v0.z, v0.w, v1.x, v1.y, v1.z, v1.w};
      unsigned short h8[8], l8v[8];
      #pragma unroll
      for (int j = 0; j < 8; ++j) {
        h8[j]  = bf16_rne(xs[j]);
        l8v[j] = bf16_rne(xs[j] - bf16_to_f(h8[j]));
      }
      int byA = tw * 4096 + ((rr * 256 + kg * 2) ^ ((rr & 7) << 4));
      *(short8*)((char*)Ahi + byA) = *(short8*)h8;
      *(short8*)((char*)Alo + byA) = *(short8*)l8v;
    }
  }

  const int ln = tid & 63, lr = ln & 15, lk = ln >> 4;
  const int w16 = tid >> 6;
  const int tw = w16 & 3, cg = w16 >> 2;
  const int tt = tg * 4 + tw;
  const unsigned short* Whi = WhiAll + (size_t)(l - 1) * G4 * HDIM;
  const unsigned short* Wlo = WloAll + (size_t)(l - 1) * G4 * HDIM;

  for (int by = 0; by < 8; ++by) {
    __syncthreads();
    if (l == 0) {
      if (tid < 256) {
        int cc = tid >> 2, kg = (tid & 3) * 8;
        int col = by * 64 + cc;
        int byB = (cc * 256 + kg * 2) ^ ((cc & 7) << 4);
        *(short8*)((char*)Bhi + byB) = *(const short8*)&W0hi[(size_t)col * 32 + kg];
        *(short8*)((char*)Blo + byB) = *(const short8*)&W0lo[(size_t)col * 32 + kg];
      }
    } else {
      int cc = tid >> 4, kg = (tid & 15) * 8;
      int col = by * 64 + cc;
      int byB = (cc * 256 + kg * 2) ^ ((cc & 7) << 4);
      *(short8*)((char*)Bhi + byB) = *(const short8*)&Whi[(size_t)col * HDIM + kg];
      *(short8*)((char*)Blo + byB) = *(const short8*)&Wlo[(size_t)col * HDIM + kg];
    }
    __syncthreads();

    f32x4 acc = {0.f, 0.f, 0.f, 0.f};
    if (l == 0) {
      int fo = (lr * 256 + lk * 16) ^ ((lr & 7) << 4);
      short8 ah = *(const short8*)((char*)Ahi + tw * 4096 + fo);
      short8 al = *(const short8*)((char*)Alo + tw * 4096 + fo);
      short8 bh = *(const short8*)((char*)Bhi + cg * 4096 + fo);
      short8 bl = *(const short8*)((char*)Blo + cg * 4096 + fo);
      acc = __builtin_amdgcn_mfma_f32_16x16x32_bf16(ah, bh, acc, 0, 0, 0);
      acc = __builtin_amdgcn_mfma_f32_16x16x32_bf16(ah, bl, acc, 0, 0, 0);
      acc = __builtin_amdgcn_mfma_f32_16x16x32_bf16(al, bh, acc, 0, 0, 0);
    } else {
      #pragma unroll
      for (int ks = 0; ks < 4; ++ks) {
        int fo = (lr * 256 + ks * 64 + lk * 16) ^ ((lr & 7) << 4);
        short8 ah = *(const short8*)((char*)Ahi + tw * 4096 + fo);
        short8 al = *(const short8*)((char*)Alo + tw * 4096 + fo);
        short8 bh = *(const short8*)((char*)Bhi + cg * 4096 + fo);
        short8 bl = *(const short8*)((char*)Blo + cg * 4096 + fo);
        acc = __builtin_amdgcn_mfma_f32_16x16x32_bf16(ah, bh, acc, 0, 0, 0);
        acc = __builtin_amdgcn_mfma_f32_16x16x32_bf16(ah, bl, acc, 0, 0, 0);
        acc = __builtin_amdgcn_mfma_f32_16x16x32_bf16(al, bh, acc, 0, 0, 0);
      }
    }
    int col = by * 64 + cg * 16 + lr;
    float bs = bih[col] + bhh[col];
    h16x4 o;
    #pragma unroll
    for (int j = 0; j < 4; ++j) o[j] = (_Float16)(acc[j] + bs);
    size_t base = ((((size_t)tt * 16 + bi) * 16) + by * 2 + (cg >> 1)) << 9;
    *(h16x4*)(XG + base + ln * 8 + (cg & 1) * 4) = o;
  }
}

// ---------------------------------------------------------------------------
// MFMA LSTM scan — col-major pp exchange (vectorized LDS):
//  * MFMA phase: pre-acts written as TWO ds_write_b128 per thread (was 8 b32)
//  * gate phase: 512 threads, each owns 4 rows x 1 hid; FOUR ds_read_b128
//    (was 8 scattered b32 across 1024 threads)
// pp[col][PPS=20 floats]: 80B stride -> (5*col)%8 quad-bank permutation,
// conflict-free b128 access. LDS instr/step ~416 -> ~260.
// ---------------------------------------------------------------------------
__global__ __launch_bounds__(1024, 4)
void scan_mfma(const _Float16* __restrict__ XGring, int tchShift,
               const unsigned short* __restrict__ WF,
               float* __restrict__ H0, float* __restrict__ H1,
               float* __restrict__ cstAll, int s, int lmin)
{
  const int l  = lmin + blockIdx.y;
  const int ch = s - l;
  const int TCHr = 1 << tchShift;
  const int t0 = ch << tchShift;
  const _Float16* __restrict__ XG =
      XGring + (size_t)(ch % RING) * (((size_t)BATCH * G4) << tchShift);
  float* __restrict__ Hout = (l & 1) ? H1 : H0;
  float* __restrict__ cst  = cstAll + (size_t)l * BATCH * HDIM;
  const int B0  = blockIdx.x * ROWS;
  const int tid = threadIdx.x;
  const int w   = tid >> 6;
  const int ln  = tid & 63;
  const int lr  = ln & 15;
  const int lk  = ln >> 4;

  __shared__ unsigned short hA[2 * ROWS * HDIM];  // 8KB, swizzled
  __shared__ float pp[G4 * PPS];                  // 40KB, col-major

  short8 bf[16];
  {
    const unsigned short* wfp = WF + (((size_t)l * 16 + w) * 16) * 512 + (size_t)ln * 8;
    #pragma unroll
    for (int f = 0; f < 16; ++f) bf[f] = *(const short8*)(wfp + (size_t)f * 512);
    #pragma unroll
    for (int f = 0; f < 16; ++f) asm("" : "+v"(bf[f]));
  }

  // Gate-thread mapping: tid<512 -> hid = tid&127, rgrp = tid>>7 (4 rows).
  const int ghid = tid & 127;
  const int rgrp = (tid >> 7) & 3;
  const bool gact = tid < 512;
  float c4[4] = {0.f, 0.f, 0.f, 0.f};
  if (gact) {
    #pragma unroll
    for (int j = 0; j < 4; ++j) {
      int row = rgrp * 4 + j;
      float hv = 0.f;
      if (t0 > 0) {
        hv   = Hout[((size_t)(B0 + row) * S_LEN + (t0 - 1)) * HDIM + ghid];
        c4[j] = cst[(B0 + row) * HDIM + ghid];
      }
      unsigned short hh = bf16_rne(hv);
      unsigned short hl = bf16_rne(hv - bf16_to_f(hh));
      int by = (row * 256 + ghid * 2) ^ ((row & 7) << 4);
      *(unsigned short*)((char*)hA + by) = hh;
      *(unsigned short*)((char*)hA + 4096 + by) = hl;
    }
  }
  __syncthreads();

  const _Float16* xgp = XG + (((size_t)blockIdx.x * 16 + w) << 9) + (ln << 3);
  float* houtB = Hout + ((size_t)B0 * S_LEN + t0) * HDIM + ghid;

  h16x8 xg_c = *(const h16x8*)xgp;

  for (int tt = 0; tt < TCHr; ++tt) {
    const h16x8 xgh = xg_c;
    const _Float16* xgn = xgp + (size_t)BATCH * G4;
    if (tt + 1 < TCHr) xg_c = *(const h16x8*)xgn;

    f32x4 acc0 = {0.f, 0.f, 0.f, 0.f}, acc1 = {0.f, 0.f, 0.f, 0.f};
    #pragma unroll
    for (int ks = 0; ks < 4; ++ks) {
      const int by = (lr * 256 + ks * 64 + lk * 16) ^ ((lr & 7) << 4);
      short8 ah = *(const short8*)((const char*)hA + by);
      short8 al = *(const short8*)((const char*)hA + 4096 + by);
      acc0 = __builtin_amdgcn_mfma_f32_16x16x32_bf16(ah, bf[(ks << 1) | 0], acc0, 0, 0, 0);
      acc0 = __builtin_amdgcn_mfma_f32_16x16x32_bf16(ah, bf[(ks << 1) | 1], acc0, 0, 0, 0);
      acc0 = __builtin_amdgcn_mfma_f32_16x16x32_bf16(al, bf[(ks << 1) | 0], acc0, 0, 0, 0);
      acc1 = __builtin_amdgcn_mfma_f32_16x16x32_bf16(ah, bf[8 | (ks << 1) | 0], acc1, 0, 0, 0);
      acc1 = __builtin_amdgcn_mfma_f32_16x16x32_bf16(ah, bf[8 | (ks << 1) | 1], acc1, 0, 0, 0);
      acc1 = __builtin_amdgcn_mfma_f32_16x16x32_bf16(al, bf[8 | (ks << 1) | 0], acc1, 0, 0, 0);
    }

    // pre-acts -> pp col-major: two b128 writes (j spans 4 consecutive rows)
    {
      const int colA = w * 32 + lr;
      f32x4 pA, pB;
      #pragma unroll
      for (int j = 0; j < 4; ++j) {
        pA[j] = acc0[j] + (float)xgh[j];
        pB[j] = acc1[j] + (float)xgh[4 + j];
      }
      *(f32x4*)&pp[colA * PPS + lk * 4] = pA;
      *(f32x4*)&pp[(colA + 16) * PPS + lk * 4] = pB;
    }
    __syncthreads();

    if (gact) {
      // four b128 reads: i/f/g/o pre-acts for 4 rows at this hid
      f32x4 pi = *(const f32x4*)&pp[(ghid)       * PPS + rgrp * 4];
      f32x4 pf = *(const f32x4*)&pp[(128 + ghid) * PPS + rgrp * 4];
      f32x4 pg = *(const f32x4*)&pp[(256 + ghid) * PPS + rgrp * 4];
      f32x4 po = *(const f32x4*)&pp[(384 + ghid) * PPS + rgrp * 4];
      #pragma unroll
      for (int j = 0; j < 4; ++j) {
        int row = rgrp * 4 + j;
        float gi = fsig(pi[j]), gf = fsig(pf[j]);
        float gg = ftanh(pg[j]), go = fsig(po[j]);
        c4[j] = fmaf(gf, c4[j], gi * gg);
        float h = go * ftanh(c4[j]);
        houtB[(size_t)row * S_LEN * HDIM + (size_t)tt * HDIM] = h;
        unsigned short hh = bf16_rne(h);
        unsigned short hl = bf16_rne(h - bf16_to_f(hh));
        int by = (row * 256 + ghid * 2) ^ ((row & 7) << 4);
        *(unsigned short*)((char*)hA + by) = hh;
        *(unsigned short*)((char*)hA + 4096 + by) = hl;
      }
    }
    __syncthreads();
    xgp = xgn;
  }
  if (gact) {
    #pragma unroll
    for (int j = 0; j < 4; ++j)
      cst[(B0 + rgrp * 4 + j) * HDIM + ghid] = c4[j];
  }
}

// ---------------------------------------------------------------------------
// Attention pass 1, MFMA (verified verbatim).
// ---------------------------------------------------------------------------
__global__ __launch_bounds__(256, 2)
void attn1_mfma(const float* __restrict__ Hs,
                const unsigned short* __restrict__ AWhi,
                const unsigned short* __restrict__ AWlo,
                const float* __restrict__ attn_b, const float* __restrict__ v_w,
                const float* __restrict__ v_b, float* __restrict__ logits)
{
  __shared__ unsigned short Ahi[64][136];
  __shared__ unsigned short Alo[64][136];
  __shared__ unsigned short Bhi[128][72];
  __shared__ unsigned short Blo[128][72];
  const int tid = threadIdx.x;
  const int rowBase = blockIdx.x * 64;

  #pragma unroll
  for (int it = 0; it < 4; ++it) {
    int idx = tid + it * 256;
    int rr  = idx >> 4;
    int kg  = (idx & 15) * 8;
    const float* ap = &Hs[(size_t)(rowBase + rr) * HDIM + kg];
    float4 v0 = *(const float4*)ap;
    float4 v1 = *(const float4*)(ap + 4);
    float xs[8] = {v0.x, v0.y, v0.z, v0.w, v1.x, v1.y, v1.z, v1.w};
    unsigned short h[8], l8[8];
    #pragma unroll
    for (int j = 0; j < 8; ++j) {
      h[j]  = bf16_rne(xs[j]);
      l8[j] = bf16_rne(xs[j] - bf16_to_f(h[j]));
    }
    *(short8*)&Ahi[rr][kg] = *(short8*)h;
    *(short8*)&Alo[rr][kg] = *(short8*)l8;
  }

  const int w    = tid >> 6;
  const int ln   = tid & 63;
  const int fr   = ln & 15;
  const int kgrp = (ln >> 4) * 8;

  f32x4 acc[8] = {};
  #pragma unroll
  for (int kh = 0; kh < 2; ++kh) {
    __syncthreads();
    #pragma unroll
    for (int it = 0; it < 4; ++it) {
      int idx = tid + it * 256;
      int cc  = idx >> 3;
      int kg  = (idx & 7) * 8;
      *(short8*)&Bhi[cc][kg] = *(const short8*)&AWhi[(size_t)cc * HDIM + kh * 64 + kg];
      *(short8*)&Blo[cc][kg] = *(const short8*)&AWlo[(size_t)cc * HDIM + kh * 64 + kg];
    }
    __syncthreads();
    #pragma unroll
    for (int ks = 0; ks < 2; ++ks) {
      const int k0 = kh * 64 + ks * 32 + kgrp;
      const int kb = ks * 32 + kgrp;
      short8 ah = *(const short8*)&Ahi[(w << 4) + fr][k0];
      short8 al = *(const short8*)&Alo[(w << 4) + fr][k0];
      #pragma unroll
      for (int nt = 0; nt < 8; ++nt) {
        short8 bh = *(const short8*)&Bhi[nt * 16 + fr][kb];
        short8 bl = *(const short8*)&Blo[nt * 16 + fr][kb];
        acc[nt] = __builtin_amdgcn_mfma_f32_16x16x32_bf16(ah, bh, acc[nt], 0, 0, 0);
        acc[nt] = __builtin_amdgcn_mfma_f32_16x16x32_bf16(ah, bl, acc[nt], 0, 0, 0);
        acc[nt] = __builtin_amdgcn_mfma_f32_16x16x32_bf16(al, bh, acc[nt], 0, 0, 0);
      }
    }
  }

  float parts[4] = {0.f, 0.f, 0.f, 0.f};
  #pragma unroll
  for (int nt = 0; nt < 8; ++nt) {
    const int col = nt * 16 + fr;
    const float ab = attn_b[col];
    const float vw = v_w[col];
    #pragma unroll
    for (int j = 0; j < 4; ++j)
      parts[j] = fmaf(ftanh(acc[nt][j] + ab), vw, parts[j]);
  }
  #pragma unroll
  for (int j = 0; j < 4; ++j) {
    #pragma unroll
    for (int off = 1; off < 16; off <<= 1)
      parts[j] += __shfl_xor(parts[j], off);
  }
  if (fr == 0) {
    const float vb = v_b[0];
    #pragma unroll
    for (int j = 0; j < 4; ++j)
      logits[rowBase + (w << 4) + ((ln >> 4) << 2) + j] = parts[j] + vb;
  }
}

// ---------------------------------------------------------------------------
// Attention pass 2 (verified verbatim).
// ---------------------------------------------------------------------------
__global__ __launch_bounds__(128)
void attn2(const float* __restrict__ Hs, const float* __restrict__ logits,
           const float* __restrict__ fc_w, const float* __restrict__ fc_b,
           float* __restrict__ outp)
{
  const int b   = blockIdx.x;
  const int tid = threadIdx.x;
  __shared__ float pbuf[S_LEN];
  __shared__ float red[4];
  __shared__ float ctx_s[HDIM];
  float l0 = logits[b * S_LEN + tid];
  float l1 = logits[b * S_LEN + 128 + tid];
  float l2 = logits[b * S_LEN + 256 + tid];
  float l3 = logits[b * S_LEN + 384 + tid];
  float m = fmaxf(fmaxf(l0, l1), fmaxf(l2, l3));
  #pragma unroll
  for (int off = 1; off < 64; off <<= 1) m = fmaxf(m, __shfl_xor(m, off));
  if ((tid & 63) == 0) red[tid >> 6] = m;
  __syncthreads();
  m = fmaxf(red[0], red[1]);
  float p0 = __expf(l0 - m), p1 = __expf(l1 - m), p2 = __expf(l2 - m), p3 = __expf(l3 - m);
  pbuf[tid] = p0; pbuf[tid + 128] = p1; pbuf[tid + 256] = p2; pbuf[tid + 384] = p3;
  float sum = (p0 + p1) + (p2 + p3);
  #pragma unroll
  for (int off = 1; off < 64; off <<= 1) sum += __shfl_xor(sum, off);
  if ((tid & 63) == 0) red[2 + (tid >> 6)] = sum;
  __syncthreads();
  const float sinv = 1.0f / (red[2] + red[3]);
  float acc = 0.f;
  const float* hp = Hs + (size_t)b * S_LEN * HDIM + tid;
  #pragma unroll 4
  for (int t = 0; t < S_LEN; ++t) acc = fmaf(pbuf[t], hp[(size_t)t * HDIM], acc);
  ctx_s[tid] = acc * sinv;
  __syncthreads();
  if (tid < 7) {
    float a = fc_b[tid];
    const float* fw = fc_w + tid * HDIM;
    #pragma unroll 8
    for (int k = 0; k < HDIM; ++k) a = fmaf(ctx_s[k], fw[k], a);
    outp[b * 7 + tid] = a;
  }
}

// ---------------------------------------------------------------------------
extern "C" void kernel_launch(void* const* d_in, const int* in_sizes, int n_in,
                              void* d_out, int out_size, void* d_ws, size_t ws_size,
                              hipStream_t stream)
{
  const float* x      = (const float*)d_in[0];
  const float* w_ih0  = (const float*)d_in[1];
  const float* w_ih   = (const float*)d_in[2];
  const float* w_hh   = (const float*)d_in[3];
  const float* b_ih   = (const float*)d_in[4];
  const float* b_hh   = (const float*)d_in[5];
  const float* attn_w = (const float*)d_in[6];
  const float* attn_b = (const float*)d_in[7];
  const float* v_w    = (const float*)d_in[8];
  const float* v_b    = (const float*)d_in[9];
  const float* fc_w   = (const float*)d_in[10];
  const float* fc_b   = (const float*)d_in[11];
  float* outp = (float*)d_out;

  const size_t szH_b  = (size_t)BATCH * S_LEN * HDIM * 4;
  const int    nWih   = (NLAYER - 1) * G4 * HDIM;
  const size_t nWF    = (size_t)NLAYER * 16 * 16 * 64 * 8;
  const int    nAW    = HDIM * HDIM;
  const int    nW0    = 512 * 32;
  const size_t fixed  = 2 * szH_b + (size_t)NLAYER * BATCH * HDIM * 4
                      + (size_t)nWih * 2 * 2 + nWF * 2 + (size_t)nAW * 2 * 2
                      + (size_t)nW0 * 2 * 2
                      + (size_t)BATCH * S_LEN * 4;

  int tchShift = -1;
  for (int sh = 6; sh >= 3; --sh) {
    size_t ringBytes = (size_t)RING * (((size_t)BATCH * G4) << sh) * 2;
    if (ws_size >= fixed + ringBytes) { tchShift = sh; break; }
  }
  if (tchShift < 0) return;
  const int TCHr = 1 << tchShift;
  const int NCHr = S_LEN >> tchShift;

  char* p = (char*)d_ws;
  _Float16* XGring = (_Float16*)p;
  p += (size_t)RING * (((size_t)BATCH * G4) << tchShift) * 2;
  float* H0  = (float*)p; p += szH_b;
  float* H1  = (float*)p; p += szH_b;
  float* cst = (float*)p; p += (size_t)NLAYER * BATCH * HDIM * 4;
  float* lg  = (float*)p; p += (size_t)BATCH * S_LEN * 4;
  unsigned short* Whi  = (unsigned short*)p; p += (size_t)nWih * 2;
  unsigned short* Wlo  = (unsigned short*)p; p += (size_t)nWih * 2;
  unsigned short* WF   = (unsigned short*)p; p += nWF * 2;
  unsigned short* AWhi = (unsigned short*)p; p += (size_t)nAW * 2;
  unsigned short* AWlo = (unsigned short*)p; p += (size_t)nAW * 2;
  unsigned short* W0hi = (unsigned short*)p; p += (size_t)nW0 * 2;
  unsigned short* W0lo = (unsigned short*)p; p += (size_t)nW0 * 2;

  split_w<<<(nWih + 255) / 256, 256, 0, stream>>>(w_ih, Whi, Wlo, nWih);
  split_w<<<(nAW + 255) / 256, 256, 0, stream>>>(attn_w, AWhi, AWlo, nAW);
  w0_prep<<<(nW0 + 255) / 256, 256, 0, stream>>>(w_ih0, W0hi, W0lo);
  whh_prep<<<(NLAYER * 16 * 16 * 64 + 255) / 256, 256, 0, stream>>>(w_hh, WF);

  const int TG = TCHr / 4;
  for (int s = 0; s <= NLAYER + NCHr - 2; ++s) {
    int lmin = (s - (NCHr - 1) > 0) ? s - (NCHr - 1) : 0;
    int lmax = (s < NLAYER - 1) ? s : NLAYER - 1;
    int np   = lmax - lmin + 1;
    gemm_st<<<dim3(NBLK, TG, np), 1024, 0, stream>>>(
        x, H0, H1, W0hi, W0lo, Whi, Wlo, b_ih, b_hh, XGring, tchShift, s, lmin);
    scan_mfma<<<dim3(NBLK, np), 1024, 0, stream>>>(
        XGring, tchShift, WF, H0, H1, cst, s, lmin);
  }

  const float* Hlast = H1;  // layer 9 (odd) writes H1
  attn1_mfma<<<dim3(BATCH * S_LEN / 64), 256, 0, stream>>>(
      Hlast, AWhi, AWlo, attn_b, v_w, v_b, lg);
  attn2<<<BATCH, 128, 0, stream>>>(Hlast, lg, fc_w, fc_b, outp);
}

// Round 17
// 2269.981 us; speedup vs baseline: 1.1540x; 1.1540x over previous
//
#include <hip/hip_runtime.h>
#include <cstdint>
#include <cstddef>

#define S_LEN 512
#define HDIM  128
#define G4    512
#define BATCH 256
#define NLAYER 10
#define ROWS  16
#define NBLK  (BATCH / ROWS)  // 16
#define RING  10

typedef float f32x4 __attribute__((ext_vector_type(4)));
typedef short short8 __attribute__((ext_vector_type(8)));
typedef _Float16 h16x4 __attribute__((ext_vector_type(4)));
typedef _Float16 h16x8 __attribute__((ext_vector_type(8)));

__device__ __forceinline__ float fsig(float x) {
  return __builtin_amdgcn_rcpf(1.0f + __expf(-x));
}
__device__ __forceinline__ float ftanh(float x) {
  return fmaf(2.0f, __builtin_amdgcn_rcpf(1.0f + __expf(-2.0f * x)), -1.0f);
}
__device__ __forceinline__ unsigned short bf16_rne(float x) {
  unsigned int u = __float_as_uint(x);
  unsigned int r = (u + 0x7fffu + ((u >> 16) & 1u)) >> 16;
  return (unsigned short)r;
}
__device__ __forceinline__ float bf16_to_f(unsigned short h) {
  return __uint_as_float(((unsigned int)h) << 16);
}

// XGS layout per chunk slot (slot = c % RING), fp16:
//   elem at ((tt*16 + bi)*16 + w)*512 + ln*8 + ct*4 + j
//   = XG[b = bi*16 + (ln>>4)*4 + j][t = t0+tt][col = w*32 + ct*16 + (ln&15)]

// ---------------------------------------------------------------------------
__global__ void split_w(const float* __restrict__ W, unsigned short* __restrict__ hi,
                        unsigned short* __restrict__ lo, int n)
{
  int i = blockIdx.x * 256 + threadIdx.x;
  if (i < n) {
    float x = W[i];
    unsigned short h = bf16_rne(x);
    hi[i] = h;
    lo[i] = bf16_rne(x - bf16_to_f(h));
  }
}

// Pad w_ih0 [512][27] -> split bf16 [512][32] (zeros in k=27..31).
__global__ void w0_prep(const float* __restrict__ W, unsigned short* __restrict__ hi,
                        unsigned short* __restrict__ lo)
{
  int i = blockIdx.x * 256 + threadIdx.x;
  if (i >= 512 * 32) return;
  int col = i >> 5, k = i & 31;
  float v = (k < 27) ? W[col * 27 + k] : 0.f;
  unsigned short h = bf16_rne(v);
  hi[i] = h;
  lo[i] = bf16_rne(v - bf16_to_f(h));
}

// ---------------------------------------------------------------------------
// Pre-arrange split Whh into MFMA B-fragment-linear order (verified round 7).
// ---------------------------------------------------------------------------
__global__ __launch_bounds__(256)
void whh_prep(const float* __restrict__ Whh, unsigned short* __restrict__ WF)
{
  int idx = blockIdx.x * 256 + threadIdx.x;
  if (idx >= NLAYER * 16 * 16 * 64) return;
  int ln = idx & 63;
  int f  = (idx >> 6) & 15;
  int w  = (idx >> 10) & 15;
  int l  = idx >> 14;
  int ct = f >> 3, ks = (f >> 1) & 3, hl = f & 1;
  int col = w * 32 + ct * 16 + (ln & 15);
  int k0  = ks * 32 + (ln >> 4) * 8;
  const float* src = Whh + ((size_t)l * G4 + col) * HDIM + k0;
  unsigned short out[8];
  #pragma unroll
  for (int j = 0; j < 8; ++j) {
    float x = src[j];
    unsigned short h = bf16_rne(x);
    out[j] = hl ? bf16_rne(x - bf16_to_f(h)) : h;
  }
  *(short8*)&WF[(size_t)idx * 8] = *(short8*)out;
}

// ---------------------------------------------------------------------------
// Unified input-projection GEMM (layers 0..9) — round-15 verbatim (verified).
// Keeps the full 3-term split (protects recurrent input precision).
// ---------------------------------------------------------------------------
__global__ __launch_bounds__(1024, 4)
void gemm_st(const float* __restrict__ x,
             const float* __restrict__ H0, const float* __restrict__ H1,
             const unsigned short* __restrict__ W0hi, const unsigned short* __restrict__ W0lo,
             const unsigned short* __restrict__ WhiAll, const unsigned short* __restrict__ WloAll,
             const float* __restrict__ bihAll, const float* __restrict__ bhhAll,
             _Float16* __restrict__ XGring, int tchShift, int s, int lmin)
{
  __shared__ unsigned short Ahi[4 * 16 * HDIM];
  __shared__ unsigned short Alo[4 * 16 * HDIM];
  __shared__ unsigned short Bhi[64 * HDIM];
  __shared__ unsigned short Blo[64 * HDIM];

  const int l  = lmin + blockIdx.z;
  const int c  = s - l;
  const int bi = blockIdx.x;
  const int tg = blockIdx.y;
  const int tid = threadIdx.x;
  const int t0 = c << tchShift;
  const size_t slotF = ((size_t)BATCH * G4) << tchShift;
  _Float16* __restrict__ XG = XGring + (size_t)(c % RING) * slotF;
  const float* bih = bihAll + l * G4;
  const float* bhh = bhhAll + l * G4;

  {
    int row = tid >> 4;
    int tw = row >> 4, rr = row & 15;
    int ks16 = tid & 15;
    int b = bi * 16 + rr;
    int t = t0 + tg * 4 + tw;
    if (l == 0) {
      if (ks16 < 4) {
        int kg = ks16 * 8;
        const float* ap = &x[((size_t)b * S_LEN + t) * 27];
        unsigned short h8[8], l8v[8];
        #pragma unroll
        for (int j = 0; j < 8; ++j) {
          int k = kg + j;
          float v = (k < 27) ? ap[k] : 0.f;
          unsigned short hh = bf16_rne(v);
          h8[j] = hh;
          l8v[j] = bf16_rne(v - bf16_to_f(hh));
        }
        int byA = tw * 4096 + ((rr * 256 + kg * 2) ^ ((rr & 7) << 4));
        *(short8*)((char*)Ahi + byA) = *(short8*)h8;
        *(short8*)((char*)Alo + byA) = *(short8*)l8v;
      }
    } else {
      int kg = ks16 * 8;
      const float* Asrc = ((l - 1) & 1) ? H1 : H0;
      const float* ap = &Asrc[((size_t)b * S_LEN + t) * HDIM + kg];
      float4 v0 = *(const float4*)ap;
      float4 v1 = *(const float4*)(ap + 4);
      float xs[8] = {v0.x, v0.y, v0.z, v0.w, v1.x, v1.y, v1.z, v1.w};
      unsigned short h8[8], l8v[8];
      #pragma unroll
      for (int j = 0; j < 8; ++j) {
        h8[j]  = bf16_rne(xs[j]);
        l8v[j] = bf16_rne(xs[j] - bf16_to_f(h8[j]));
      }
      int byA = tw * 4096 + ((rr * 256 + kg * 2) ^ ((rr & 7) << 4));
      *(short8*)((char*)Ahi + byA) = *(short8*)h8;
      *(short8*)((char*)Alo + byA) = *(short8*)l8v;
    }
  }

  const int ln = tid & 63, lr = ln & 15, lk = ln >> 4;
  const int w16 = tid >> 6;
  const int tw = w16 & 3, cg = w16 >> 2;
  const int tt = tg * 4 + tw;
  const unsigned short* Whi = WhiAll + (size_t)(l - 1) * G4 * HDIM;
  const unsigned short* Wlo = WloAll + (size_t)(l - 1) * G4 * HDIM;

  for (int by = 0; by < 8; ++by) {
    __syncthreads();
    if (l == 0) {
      if (tid < 256) {
        int cc = tid >> 2, kg = (tid & 3) * 8;
        int col = by * 64 + cc;
        int byB = (cc * 256 + kg * 2) ^ ((cc & 7) << 4);
        *(short8*)((char*)Bhi + byB) = *(const short8*)&W0hi[(size_t)col * 32 + kg];
        *(short8*)((char*)Blo + byB) = *(const short8*)&W0lo[(size_t)col * 32 + kg];
      }
    } else {
      int cc = tid >> 4, kg = (tid & 15) * 8;
      int col = by * 64 + cc;
      int byB = (cc * 256 + kg * 2) ^ ((cc & 7) << 4);
      *(short8*)((char*)Bhi + byB) = *(const short8*)&Whi[(size_t)col * HDIM + kg];
      *(short8*)((char*)Blo + byB) = *(const short8*)&Wlo[(size_t)col * HDIM + kg];
    }
    __syncthreads();

    f32x4 acc = {0.f, 0.f, 0.f, 0.f};
    if (l == 0) {
      int fo = (lr * 256 + lk * 16) ^ ((lr & 7) << 4);
      short8 ah = *(const short8*)((char*)Ahi + tw * 4096 + fo);
      short8 al = *(const short8*)((char*)Alo + tw * 4096 + fo);
      short8 bh = *(const short8*)((char*)Bhi + cg * 4096 + fo);
      short8 bl = *(const short8*)((char*)Blo + cg * 4096 + fo);
      acc = __builtin_amdgcn_mfma_f32_16x16x32_bf16(ah, bh, acc, 0, 0, 0);
      acc = __builtin_amdgcn_mfma_f32_16x16x32_bf16(ah, bl, acc, 0, 0, 0);
      acc = __builtin_amdgcn_mfma_f32_16x16x32_bf16(al, bh, acc, 0, 0, 0);
    } else {
      #pragma unroll
      for (int ks = 0; ks < 4; ++ks) {
        int fo = (lr * 256 + ks * 64 + lk * 16) ^ ((lr & 7) << 4);
        short8 ah = *(const short8*)((char*)Ahi + tw * 4096 + fo);
        short8 al = *(const short8*)((char*)Alo + tw * 4096 + fo);
        short8 bh = *(const short8*)((char*)Bhi + cg * 4096 + fo);
        short8 bl = *(const short8*)((char*)Blo + cg * 4096 + fo);
        acc = __builtin_amdgcn_mfma_f32_16x16x32_bf16(ah, bh, acc, 0, 0, 0);
        acc = __builtin_amdgcn_mfma_f32_16x16x32_bf16(ah, bl, acc, 0, 0, 0);
        acc = __builtin_amdgcn_mfma_f32_16x16x32_bf16(al, bh, acc, 0, 0, 0);
      }
    }
    int col = by * 64 + cg * 16 + lr;
    float bs = bih[col] + bhh[col];
    h16x4 o;
    #pragma unroll
    for (int j = 0; j < 4; ++j) o[j] = (_Float16)(acc[j] + bs);
    size_t base = ((((size_t)tt * 16 + bi) * 16) + by * 2 + (cg >> 1)) << 9;
    *(h16x4*)(XG + base + ln * 8 + (cg & 1) * 4) = o;
  }
}

// ---------------------------------------------------------------------------
// MFMA LSTM scan — round-15 structure (row-major swizzled pp, proven 64us)
// with the A-side lo term DROPPED: h quantized to bf16 (hi plane only),
// weights keep hi+lo. Per wave-step: 4 hA b128 reads (was 8), 16 MFMAs
// (was 24); hA lo plane removed (-4KB LDS, -lo writes).
// ---------------------------------------------------------------------------
__global__ __launch_bounds__(1024, 4)
void scan_mfma(const _Float16* __restrict__ XGring, int tchShift,
               const unsigned short* __restrict__ WF,
               float* __restrict__ H0, float* __restrict__ H1,
               float* __restrict__ cstAll, int s, int lmin)
{
  const int l  = lmin + blockIdx.y;
  const int ch = s - l;
  const int TCHr = 1 << tchShift;
  const int t0 = ch << tchShift;
  const _Float16* __restrict__ XG =
      XGring + (size_t)(ch % RING) * (((size_t)BATCH * G4) << tchShift);
  float* __restrict__ Hout = (l & 1) ? H1 : H0;
  float* __restrict__ cst  = cstAll + (size_t)l * BATCH * HDIM;
  const int B0  = blockIdx.x * ROWS;
  const int tid = threadIdx.x;
  const int w   = tid >> 6;
  const int ln  = tid & 63;
  const int lr  = ln & 15;
  const int lk  = ln >> 4;

  __shared__ unsigned short hA[ROWS * HDIM];      // 4KB, hi plane only, swizzled
  __shared__ float pp[ROWS * G4];                 // 32KB, pre-acts, swizzled

  short8 bf[16];
  {
    const unsigned short* wfp = WF + (((size_t)l * 16 + w) * 16) * 512 + (size_t)ln * 8;
    #pragma unroll
    for (int f = 0; f < 16; ++f) bf[f] = *(const short8*)(wfp + (size_t)f * 512);
    #pragma unroll
    for (int f = 0; f < 16; ++f) asm("" : "+v"(bf[f]));
  }

  const int grow0 = tid >> 7;
  const int grow1 = grow0 + 8;
  const int ghid  = tid & 127;
  float c0 = 0.f, c1 = 0.f;
  {
    float h0v = 0.f, h1v = 0.f;
    if (t0 > 0) {
      h0v = Hout[((size_t)(B0 + grow0) * S_LEN + (t0 - 1)) * HDIM + ghid];
      h1v = Hout[((size_t)(B0 + grow1) * S_LEN + (t0 - 1)) * HDIM + ghid];
      c0 = cst[(B0 + grow0) * HDIM + ghid];
      c1 = cst[(B0 + grow1) * HDIM + ghid];
    }
    int by0 = (grow0 * 256 + ghid * 2) ^ ((grow0 & 7) << 4);
    int by1 = (grow1 * 256 + ghid * 2) ^ ((grow1 & 7) << 4);
    *(unsigned short*)((char*)hA + by0) = bf16_rne(h0v);
    *(unsigned short*)((char*)hA + by1) = bf16_rne(h1v);
  }
  __syncthreads();

  const _Float16* xgp = XG + (((size_t)blockIdx.x * 16 + w) << 9) + (ln << 3);
  float* hout0 = Hout + ((size_t)(B0 + grow0) * S_LEN + t0) * HDIM + ghid;
  float* hout1 = Hout + ((size_t)(B0 + grow1) * S_LEN + t0) * HDIM + ghid;

  // 1-step software pipeline on xg (one 16B load per step).
  h16x8 xg_c = *(const h16x8*)xgp;

  for (int tt = 0; tt < TCHr; ++tt) {
    const h16x8 xgh = xg_c;
    const _Float16* xgn = xgp + (size_t)BATCH * G4;
    if (tt + 1 < TCHr) xg_c = *(const h16x8*)xgn;

    f32x4 acc0 = {0.f, 0.f, 0.f, 0.f}, acc1 = {0.f, 0.f, 0.f, 0.f};
    #pragma unroll
    for (int ks = 0; ks < 4; ++ks) {
      const int by = (lr * 256 + ks * 64 + lk * 16) ^ ((lr & 7) << 4);
      short8 ah = *(const short8*)((const char*)hA + by);
      acc0 = __builtin_amdgcn_mfma_f32_16x16x32_bf16(ah, bf[(ks << 1) | 0], acc0, 0, 0, 0);
      acc0 = __builtin_amdgcn_mfma_f32_16x16x32_bf16(ah, bf[(ks << 1) | 1], acc0, 0, 0, 0);
      acc1 = __builtin_amdgcn_mfma_f32_16x16x32_bf16(ah, bf[8 | (ks << 1) | 0], acc1, 0, 0, 0);
      acc1 = __builtin_amdgcn_mfma_f32_16x16x32_bf16(ah, bf[8 | (ks << 1) | 1], acc1, 0, 0, 0);
    }

    #pragma unroll
    for (int j = 0; j < 4; ++j) {
      int r16 = lk * 4 + j;
      int colA = w * 32 + lr;
      int byA = (r16 * 2048 + colA * 4) ^ ((r16 & 3) << 5);
      *(float*)((char*)pp + byA) = acc0[j] + (float)xgh[j];
      int colB = colA + 16;
      int byB = (r16 * 2048 + colB * 4) ^ ((r16 & 3) << 5);
      *(float*)((char*)pp + byB) = acc1[j] + (float)xgh[4 + j];
    }
    __syncthreads();

    {
      int b0 = grow0 * 2048, x0 = (grow0 & 3) << 5;
      float pi = *(const float*)((const char*)pp + ((b0 + (ghid)       * 4) ^ x0));
      float pf = *(const float*)((const char*)pp + ((b0 + (128 + ghid) * 4) ^ x0));
      float pg = *(const float*)((const char*)pp + ((b0 + (256 + ghid) * 4) ^ x0));
      float po = *(const float*)((const char*)pp + ((b0 + (384 + ghid) * 4) ^ x0));
      float gi = fsig(pi), gf = fsig(pf), gg = ftanh(pg), go = fsig(po);
      c0 = fmaf(gf, c0, gi * gg);
      float h0 = go * ftanh(c0);

      int b1 = grow1 * 2048, x1 = (grow1 & 3) << 5;
      float qi = *(const float*)((const char*)pp + ((b1 + (ghid)       * 4) ^ x1));
      float qf = *(const float*)((const char*)pp + ((b1 + (128 + ghid) * 4) ^ x1));
      float qg = *(const float*)((const char*)pp + ((b1 + (256 + ghid) * 4) ^ x1));
      float qo = *(const float*)((const char*)pp + ((b1 + (384 + ghid) * 4) ^ x1));
      float hi_ = fsig(qi), hf = fsig(qf), hg = ftanh(qg), ho = fsig(qo);
      c1 = fmaf(hf, c1, hi_ * hg);
      float h1 = ho * ftanh(c1);

      hout0[0] = h0;
      hout1[0] = h1;
      int by0 = (grow0 * 256 + ghid * 2) ^ ((grow0 & 7) << 4);
      int by1 = (grow1 * 256 + ghid * 2) ^ ((grow1 & 7) << 4);
      *(unsigned short*)((char*)hA + by0) = bf16_rne(h0);
      *(unsigned short*)((char*)hA + by1) = bf16_rne(h1);
    }
    __syncthreads();
    xgp = xgn;
    hout0 += HDIM;
    hout1 += HDIM;
  }
  cst[(B0 + grow0) * HDIM + ghid] = c0;
  cst[(B0 + grow1) * HDIM + ghid] = c1;
}

// ---------------------------------------------------------------------------
// Attention pass 1, MFMA (verified verbatim).
// ---------------------------------------------------------------------------
__global__ __launch_bounds__(256, 2)
void attn1_mfma(const float* __restrict__ Hs,
                const unsigned short* __restrict__ AWhi,
                const unsigned short* __restrict__ AWlo,
                const float* __restrict__ attn_b, const float* __restrict__ v_w,
                const float* __restrict__ v_b, float* __restrict__ logits)
{
  __shared__ unsigned short Ahi[64][136];
  __shared__ unsigned short Alo[64][136];
  __shared__ unsigned short Bhi[128][72];
  __shared__ unsigned short Blo[128][72];
  const int tid = threadIdx.x;
  const int rowBase = blockIdx.x * 64;

  #pragma unroll
  for (int it = 0; it < 4; ++it) {
    int idx = tid + it * 256;
    int rr  = idx >> 4;
    int kg  = (idx & 15) * 8;
    const float* ap = &Hs[(size_t)(rowBase + rr) * HDIM + kg];
    float4 v0 = *(const float4*)ap;
    float4 v1 = *(const float4*)(ap + 4);
    float xs[8] = {v0.x, v0.y, v0.z, v0.w, v1.x, v1.y, v1.z, v1.w};
    unsigned short h[8], l8[8];
    #pragma unroll
    for (int j = 0; j < 8; ++j) {
      h[j]  = bf16_rne(xs[j]);
      l8[j] = bf16_rne(xs[j] - bf16_to_f(h[j]));
    }
    *(short8*)&Ahi[rr][kg] = *(short8*)h;
    *(short8*)&Alo[rr][kg] = *(short8*)l8;
  }

  const int w    = tid >> 6;
  const int ln   = tid & 63;
  const int fr   = ln & 15;
  const int kgrp = (ln >> 4) * 8;

  f32x4 acc[8] = {};
  #pragma unroll
  for (int kh = 0; kh < 2; ++kh) {
    __syncthreads();
    #pragma unroll
    for (int it = 0; it < 4; ++it) {
      int idx = tid + it * 256;
      int cc  = idx >> 3;
      int kg  = (idx & 7) * 8;
      *(short8*)&Bhi[cc][kg] = *(const short8*)&AWhi[(size_t)cc * HDIM + kh * 64 + kg];
      *(short8*)&Blo[cc][kg] = *(const short8*)&AWlo[(size_t)cc * HDIM + kh * 64 + kg];
    }
    __syncthreads();
    #pragma unroll
    for (int ks = 0; ks < 2; ++ks) {
      const int k0 = kh * 64 + ks * 32 + kgrp;
      const int kb = ks * 32 + kgrp;
      short8 ah = *(const short8*)&Ahi[(w << 4) + fr][k0];
      short8 al = *(const short8*)&Alo[(w << 4) + fr][k0];
      #pragma unroll
      for (int nt = 0; nt < 8; ++nt) {
        short8 bh = *(const short8*)&Bhi[nt * 16 + fr][kb];
        short8 bl = *(const short8*)&Blo[nt * 16 + fr][kb];
        acc[nt] = __builtin_amdgcn_mfma_f32_16x16x32_bf16(ah, bh, acc[nt], 0, 0, 0);
        acc[nt] = __builtin_amdgcn_mfma_f32_16x16x32_bf16(ah, bl, acc[nt], 0, 0, 0);
        acc[nt] = __builtin_amdgcn_mfma_f32_16x16x32_bf16(al, bh, acc[nt], 0, 0, 0);
      }
    }
  }

  float parts[4] = {0.f, 0.f, 0.f, 0.f};
  #pragma unroll
  for (int nt = 0; nt < 8; ++nt) {
    const int col = nt * 16 + fr;
    const float ab = attn_b[col];
    const float vw = v_w[col];
    #pragma unroll
    for (int j = 0; j < 4; ++j)
      parts[j] = fmaf(ftanh(acc[nt][j] + ab), vw, parts[j]);
  }
  #pragma unroll
  for (int j = 0; j < 4; ++j) {
    #pragma unroll
    for (int off = 1; off < 16; off <<= 1)
      parts[j] += __shfl_xor(parts[j], off);
  }
  if (fr == 0) {
    const float vb = v_b[0];
    #pragma unroll
    for (int j = 0; j < 4; ++j)
      logits[rowBase + (w << 4) + ((ln >> 4) << 2) + j] = parts[j] + vb;
  }
}

// ---------------------------------------------------------------------------
// Attention pass 2 (verified verbatim).
// ---------------------------------------------------------------------------
__global__ __launch_bounds__(128)
void attn2(const float* __restrict__ Hs, const float* __restrict__ logits,
           const float* __restrict__ fc_w, const float* __restrict__ fc_b,
           float* __restrict__ outp)
{
  const int b   = blockIdx.x;
  const int tid = threadIdx.x;
  __shared__ float pbuf[S_LEN];
  __shared__ float red[4];
  __shared__ float ctx_s[HDIM];
  float l0 = logits[b * S_LEN + tid];
  float l1 = logits[b * S_LEN + 128 + tid];
  float l2 = logits[b * S_LEN + 256 + tid];
  float l3 = logits[b * S_LEN + 384 + tid];
  float m = fmaxf(fmaxf(l0, l1), fmaxf(l2, l3));
  #pragma unroll
  for (int off = 1; off < 64; off <<= 1) m = fmaxf(m, __shfl_xor(m, off));
  if ((tid & 63) == 0) red[tid >> 6] = m;
  __syncthreads();
  m = fmaxf(red[0], red[1]);
  float p0 = __expf(l0 - m), p1 = __expf(l1 - m), p2 = __expf(l2 - m), p3 = __expf(l3 - m);
  pbuf[tid] = p0; pbuf[tid + 128] = p1; pbuf[tid + 256] = p2; pbuf[tid + 384] = p3;
  float sum = (p0 + p1) + (p2 + p3);
  #pragma unroll
  for (int off = 1; off < 64; off <<= 1) sum += __shfl_xor(sum, off);
  if ((tid & 63) == 0) red[2 + (tid >> 6)] = sum;
  __syncthreads();
  const float sinv = 1.0f / (red[2] + red[3]);
  float acc = 0.f;
  const float* hp = Hs + (size_t)b * S_LEN * HDIM + tid;
  #pragma unroll 4
  for (int t = 0; t < S_LEN; ++t) acc = fmaf(pbuf[t], hp[(size_t)t * HDIM], acc);
  ctx_s[tid] = acc * sinv;
  __syncthreads();
  if (tid < 7) {
    float a = fc_b[tid];
    const float* fw = fc_w + tid * HDIM;
    #pragma unroll 8
    for (int k = 0; k < HDIM; ++k) a = fmaf(ctx_s[k], fw[k], a);
    outp[b * 7 + tid] = a;
  }
}

// ---------------------------------------------------------------------------
extern "C" void kernel_launch(void* const* d_in, const int* in_sizes, int n_in,
                              void* d_out, int out_size, void* d_ws, size_t ws_size,
                              hipStream_t stream)
{
  const float* x      = (const float*)d_in[0];
  const float* w_ih0  = (const float*)d_in[1];
  const float* w_ih   = (const float*)d_in[2];
  const float* w_hh   = (const float*)d_in[3];
  const float* b_ih   = (const float*)d_in[4];
  const float* b_hh   = (const float*)d_in[5];
  const float* attn_w = (const float*)d_in[6];
  const float* attn_b = (const float*)d_in[7];
  const float* v_w    = (const float*)d_in[8];
  const float* v_b    = (const float*)d_in[9];
  const float* fc_w   = (const float*)d_in[10];
  const float* fc_b   = (const float*)d_in[11];
  float* outp = (float*)d_out;

  const size_t szH_b  = (size_t)BATCH * S_LEN * HDIM * 4;
  const int    nWih   = (NLAYER - 1) * G4 * HDIM;
  const size_t nWF    = (size_t)NLAYER * 16 * 16 * 64 * 8;
  const int    nAW    = HDIM * HDIM;
  const int    nW0    = 512 * 32;
  const size_t fixed  = 2 * szH_b + (size_t)NLAYER * BATCH * HDIM * 4
                      + (size_t)nWih * 2 * 2 + nWF * 2 + (size_t)nAW * 2 * 2
                      + (size_t)nW0 * 2 * 2
                      + (size_t)BATCH * S_LEN * 4;

  int tchShift = -1;
  for (int sh = 6; sh >= 3; --sh) {
    size_t ringBytes = (size_t)RING * (((size_t)BATCH * G4) << sh) * 2;
    if (ws_size >= fixed + ringBytes) { tchShift = sh; break; }
  }
  if (tchShift < 0) return;
  const int TCHr = 1 << tchShift;
  const int NCHr = S_LEN >> tchShift;

  char* p = (char*)d_ws;
  _Float16* XGring = (_Float16*)p;
  p += (size_t)RING * (((size_t)BATCH * G4) << tchShift) * 2;
  float* H0  = (float*)p; p += szH_b;
  float* H1  = (float*)p; p += szH_b;
  float* cst = (float*)p; p += (size_t)NLAYER * BATCH * HDIM * 4;
  float* lg  = (float*)p; p += (size_t)BATCH * S_LEN * 4;
  unsigned short* Whi  = (unsigned short*)p; p += (size_t)nWih * 2;
  unsigned short* Wlo  = (unsigned short*)p; p += (size_t)nWih * 2;
  unsigned short* WF   = (unsigned short*)p; p += nWF * 2;
  unsigned short* AWhi = (unsigned short*)p; p += (size_t)nAW * 2;
  unsigned short* AWlo = (unsigned short*)p; p += (size_t)nAW * 2;
  unsigned short* W0hi = (unsigned short*)p; p += (size_t)nW0 * 2;
  unsigned short* W0lo = (unsigned short*)p; p += (size_t)nW0 * 2;

  split_w<<<(nWih + 255) / 256, 256, 0, stream>>>(w_ih, Whi, Wlo, nWih);
  split_w<<<(nAW + 255) / 256, 256, 0, stream>>>(attn_w, AWhi, AWlo, nAW);
  w0_prep<<<(nW0 + 255) / 256, 256, 0, stream>>>(w_ih0, W0hi, W0lo);
  whh_prep<<<(NLAYER * 16 * 16 * 64 + 255) / 256, 256, 0, stream>>>(w_hh, WF);

  const int TG = TCHr / 4;
  for (int s = 0; s <= NLAYER + NCHr - 2; ++s) {
    int lmin = (s - (NCHr - 1) > 0) ? s - (NCHr - 1) : 0;
    int lmax = (s < NLAYER - 1) ? s : NLAYER - 1;
    int np   = lmax - lmin + 1;
    gemm_st<<<dim3(NBLK, TG, np), 1024, 0, stream>>>(
        x, H0, H1, W0hi, W0lo, Whi, Wlo, b_ih, b_hh, XGring, tchShift, s, lmin);
    scan_mfma<<<dim3(NBLK, np), 1024, 0, stream>>>(
        XGring, tchShift, WF, H0, H1, cst, s, lmin);
  }

  const float* Hlast = H1;  // layer 9 (odd) writes H1
  attn1_mfma<<<dim3(BATCH * S_LEN / 64), 256, 0, stream>>>(
      Hlast, AWhi, AWlo, attn_b, v_w, v_b, lg);
  attn2<<<BATCH, 128, 0, stream>>>(Hlast, lg, fc_w, fc_b, outp);
}

// Round 18
// 2149.490 us; speedup vs baseline: 1.2187x; 1.0561x over previous
//
#include <hip/hip_runtime.h>
#include <cstdint>
#include <cstddef>

#define S_LEN 512
#define HDIM  128
#define G4    512
#define BATCH 256
#define NLAYER 10
#define ROWS  16
#define NBLK  (BATCH / ROWS)  // 16
#define RING  10

typedef float f32x4 __attribute__((ext_vector_type(4)));
typedef short short8 __attribute__((ext_vector_type(8)));
typedef _Float16 h16x4 __attribute__((ext_vector_type(4)));
typedef _Float16 h16x8 __attribute__((ext_vector_type(8)));

__device__ __forceinline__ float fsig(float x) {
  return __builtin_amdgcn_rcpf(1.0f + __expf(-x));
}
__device__ __forceinline__ float ftanh(float x) {
  return fmaf(2.0f, __builtin_amdgcn_rcpf(1.0f + __expf(-2.0f * x)), -1.0f);
}
__device__ __forceinline__ unsigned short bf16_rne(float x) {
  unsigned int u = __float_as_uint(x);
  unsigned int r = (u + 0x7fffu + ((u >> 16) & 1u)) >> 16;
  return (unsigned short)r;
}
__device__ __forceinline__ float bf16_to_f(unsigned short h) {
  return __uint_as_float(((unsigned int)h) << 16);
}

// XGS layout per chunk slot (slot = c % RING), fp16:
//   elem at ((tt*16 + bi)*16 + w)*512 + ln*8 + ct*4 + j
//   = XG[b = bi*16 + (ln>>4)*4 + j][t = t0+tt][col = w*32 + ct*16 + (ln&15)]

// ---------------------------------------------------------------------------
__global__ void split_w(const float* __restrict__ W, unsigned short* __restrict__ hi,
                        unsigned short* __restrict__ lo, int n)
{
  int i = blockIdx.x * 256 + threadIdx.x;
  if (i < n) {
    float x = W[i];
    unsigned short h = bf16_rne(x);
    hi[i] = h;
    lo[i] = bf16_rne(x - bf16_to_f(h));
  }
}

// Pad w_ih0 [512][27] -> split bf16 [512][32] (zeros in k=27..31).
__global__ void w0_prep(const float* __restrict__ W, unsigned short* __restrict__ hi,
                        unsigned short* __restrict__ lo)
{
  int i = blockIdx.x * 256 + threadIdx.x;
  if (i >= 512 * 32) return;
  int col = i >> 5, k = i & 31;
  float v = (k < 27) ? W[col * 27 + k] : 0.f;
  unsigned short h = bf16_rne(v);
  hi[i] = h;
  lo[i] = bf16_rne(v - bf16_to_f(h));
}

// ---------------------------------------------------------------------------
// Pre-arrange split Whh into MFMA B-fragment-linear order (verified round 7).
// ---------------------------------------------------------------------------
__global__ __launch_bounds__(256)
void whh_prep(const float* __restrict__ Whh, unsigned short* __restrict__ WF)
{
  int idx = blockIdx.x * 256 + threadIdx.x;
  if (idx >= NLAYER * 16 * 16 * 64) return;
  int ln = idx & 63;
  int f  = (idx >> 6) & 15;
  int w  = (idx >> 10) & 15;
  int l  = idx >> 14;
  int ct = f >> 3, ks = (f >> 1) & 3, hl = f & 1;
  int col = w * 32 + ct * 16 + (ln & 15);
  int k0  = ks * 32 + (ln >> 4) * 8;
  const float* src = Whh + ((size_t)l * G4 + col) * HDIM + k0;
  unsigned short out[8];
  #pragma unroll
  for (int j = 0; j < 8; ++j) {
    float x = src[j];
    unsigned short h = bf16_rne(x);
    out[j] = hl ? bf16_rne(x - bf16_to_f(h)) : h;
  }
  *(short8*)&WF[(size_t)idx * 8] = *(short8*)out;
}

// ---------------------------------------------------------------------------
// Unified input-projection GEMM (layers 0..9), 1024 threads, 3D grid.
// A-side lo DROPPED (round-17-validated trick): A bf16 hi only; B keeps
// hi+lo. Per ks: 3 LDS reads + 2 MFMAs (was 4 + 3). LDS 64KB -> 48KB.
// ---------------------------------------------------------------------------
__global__ __launch_bounds__(1024, 4)
void gemm_st(const float* __restrict__ x,
             const float* __restrict__ H0, const float* __restrict__ H1,
             const unsigned short* __restrict__ W0hi, const unsigned short* __restrict__ W0lo,
             const unsigned short* __restrict__ WhiAll, const unsigned short* __restrict__ WloAll,
             const float* __restrict__ bihAll, const float* __restrict__ bhhAll,
             _Float16* __restrict__ XGring, int tchShift, int s, int lmin)
{
  __shared__ unsigned short Ahi[4 * 16 * HDIM];   // 16KB, [tw] 4KB, swizzled
  __shared__ unsigned short Bhi[64 * HDIM];       // 16KB, swizzled
  __shared__ unsigned short Blo[64 * HDIM];

  const int l  = lmin + blockIdx.z;
  const int c  = s - l;
  const int bi = blockIdx.x;
  const int tg = blockIdx.y;
  const int tid = threadIdx.x;
  const int t0 = c << tchShift;
  const size_t slotF = ((size_t)BATCH * G4) << tchShift;
  _Float16* __restrict__ XG = XGring + (size_t)(c % RING) * slotF;
  const float* bih = bihAll + l * G4;
  const float* bhh = bhhAll + l * G4;

  // ---- stage A: 64 rows (16b x 4t) x K -> bf16 hi, swizzled ----
  {
    int row = tid >> 4;
    int tw = row >> 4, rr = row & 15;
    int ks16 = tid & 15;
    int b = bi * 16 + rr;
    int t = t0 + tg * 4 + tw;
    if (l == 0) {
      if (ks16 < 4) {
        int kg = ks16 * 8;
        const float* ap = &x[((size_t)b * S_LEN + t) * 27];
        unsigned short h8[8];
        #pragma unroll
        for (int j = 0; j < 8; ++j) {
          int k = kg + j;
          float v = (k < 27) ? ap[k] : 0.f;
          h8[j] = bf16_rne(v);
        }
        int byA = tw * 4096 + ((rr * 256 + kg * 2) ^ ((rr & 7) << 4));
        *(short8*)((char*)Ahi + byA) = *(short8*)h8;
      }
    } else {
      int kg = ks16 * 8;
      const float* Asrc = ((l - 1) & 1) ? H1 : H0;
      const float* ap = &Asrc[((size_t)b * S_LEN + t) * HDIM + kg];
      float4 v0 = *(const float4*)ap;
      float4 v1 = *(const float4*)(ap + 4);
      float xs[8] = {v0.x, v0.y, v0.z, v0.w, v1.x, v1.y, v1.z, v1.w};
      unsigned short h8[8];
      #pragma unroll
      for (int j = 0; j < 8; ++j) h8[j] = bf16_rne(xs[j]);
      int byA = tw * 4096 + ((rr * 256 + kg * 2) ^ ((rr & 7) << 4));
      *(short8*)((char*)Ahi + byA) = *(short8*)h8;
    }
  }

  const int ln = tid & 63, lr = ln & 15, lk = ln >> 4;
  const int w16 = tid >> 6;
  const int tw = w16 & 3, cg = w16 >> 2;
  const int tt = tg * 4 + tw;
  const unsigned short* Whi = WhiAll + (size_t)(l - 1) * G4 * HDIM;  // used only l>0
  const unsigned short* Wlo = WloAll + (size_t)(l - 1) * G4 * HDIM;

  for (int by = 0; by < 8; ++by) {
    __syncthreads();   // A visible (by=0) / prior B reads done
    if (l == 0) {
      if (tid < 256) {
        int cc = tid >> 2, kg = (tid & 3) * 8;
        int col = by * 64 + cc;
        int byB = (cc * 256 + kg * 2) ^ ((cc & 7) << 4);
        *(short8*)((char*)Bhi + byB) = *(const short8*)&W0hi[(size_t)col * 32 + kg];
        *(short8*)((char*)Blo + byB) = *(const short8*)&W0lo[(size_t)col * 32 + kg];
      }
    } else {
      int cc = tid >> 4, kg = (tid & 15) * 8;
      int col = by * 64 + cc;
      int byB = (cc * 256 + kg * 2) ^ ((cc & 7) << 4);
      *(short8*)((char*)Bhi + byB) = *(const short8*)&Whi[(size_t)col * HDIM + kg];
      *(short8*)((char*)Blo + byB) = *(const short8*)&Wlo[(size_t)col * HDIM + kg];
    }
    __syncthreads();

    f32x4 acc = {0.f, 0.f, 0.f, 0.f};
    if (l == 0) {
      int fo = (lr * 256 + lk * 16) ^ ((lr & 7) << 4);
      short8 ah = *(const short8*)((char*)Ahi + tw * 4096 + fo);
      short8 bh = *(const short8*)((char*)Bhi + cg * 4096 + fo);
      short8 bl = *(const short8*)((char*)Blo + cg * 4096 + fo);
      acc = __builtin_amdgcn_mfma_f32_16x16x32_bf16(ah, bh, acc, 0, 0, 0);
      acc = __builtin_amdgcn_mfma_f32_16x16x32_bf16(ah, bl, acc, 0, 0, 0);
    } else {
      #pragma unroll
      for (int ks = 0; ks < 4; ++ks) {
        int fo = (lr * 256 + ks * 64 + lk * 16) ^ ((lr & 7) << 4);
        short8 ah = *(const short8*)((char*)Ahi + tw * 4096 + fo);
        short8 bh = *(const short8*)((char*)Bhi + cg * 4096 + fo);
        short8 bl = *(const short8*)((char*)Blo + cg * 4096 + fo);
        acc = __builtin_amdgcn_mfma_f32_16x16x32_bf16(ah, bh, acc, 0, 0, 0);
        acc = __builtin_amdgcn_mfma_f32_16x16x32_bf16(ah, bl, acc, 0, 0, 0);
      }
    }
    int col = by * 64 + cg * 16 + lr;
    float bs = bih[col] + bhh[col];
    h16x4 o;
    #pragma unroll
    for (int j = 0; j < 4; ++j) o[j] = (_Float16)(acc[j] + bs);
    size_t base = ((((size_t)tt * 16 + bi) * 16) + by * 2 + (cg >> 1)) << 9;
    *(h16x4*)(XG + base + ln * 8 + (cg & 1) * 4) = o;
  }
}

// ---------------------------------------------------------------------------
// MFMA LSTM scan — round-17 verbatim (verified: bf16-h hi-only, 16 MFMAs,
// 4 hA b128 reads per wave-step).
// ---------------------------------------------------------------------------
__global__ __launch_bounds__(1024, 4)
void scan_mfma(const _Float16* __restrict__ XGring, int tchShift,
               const unsigned short* __restrict__ WF,
               float* __restrict__ H0, float* __restrict__ H1,
               float* __restrict__ cstAll, int s, int lmin)
{
  const int l  = lmin + blockIdx.y;
  const int ch = s - l;
  const int TCHr = 1 << tchShift;
  const int t0 = ch << tchShift;
  const _Float16* __restrict__ XG =
      XGring + (size_t)(ch % RING) * (((size_t)BATCH * G4) << tchShift);
  float* __restrict__ Hout = (l & 1) ? H1 : H0;
  float* __restrict__ cst  = cstAll + (size_t)l * BATCH * HDIM;
  const int B0  = blockIdx.x * ROWS;
  const int tid = threadIdx.x;
  const int w   = tid >> 6;
  const int ln  = tid & 63;
  const int lr  = ln & 15;
  const int lk  = ln >> 4;

  __shared__ unsigned short hA[ROWS * HDIM];      // 4KB, hi plane only, swizzled
  __shared__ float pp[ROWS * G4];                 // 32KB, pre-acts, swizzled

  short8 bf[16];
  {
    const unsigned short* wfp = WF + (((size_t)l * 16 + w) * 16) * 512 + (size_t)ln * 8;
    #pragma unroll
    for (int f = 0; f < 16; ++f) bf[f] = *(const short8*)(wfp + (size_t)f * 512);
    #pragma unroll
    for (int f = 0; f < 16; ++f) asm("" : "+v"(bf[f]));
  }

  const int grow0 = tid >> 7;
  const int grow1 = grow0 + 8;
  const int ghid  = tid & 127;
  float c0 = 0.f, c1 = 0.f;
  {
    float h0v = 0.f, h1v = 0.f;
    if (t0 > 0) {
      h0v = Hout[((size_t)(B0 + grow0) * S_LEN + (t0 - 1)) * HDIM + ghid];
      h1v = Hout[((size_t)(B0 + grow1) * S_LEN + (t0 - 1)) * HDIM + ghid];
      c0 = cst[(B0 + grow0) * HDIM + ghid];
      c1 = cst[(B0 + grow1) * HDIM + ghid];
    }
    int by0 = (grow0 * 256 + ghid * 2) ^ ((grow0 & 7) << 4);
    int by1 = (grow1 * 256 + ghid * 2) ^ ((grow1 & 7) << 4);
    *(unsigned short*)((char*)hA + by0) = bf16_rne(h0v);
    *(unsigned short*)((char*)hA + by1) = bf16_rne(h1v);
  }
  __syncthreads();

  const _Float16* xgp = XG + (((size_t)blockIdx.x * 16 + w) << 9) + (ln << 3);
  float* hout0 = Hout + ((size_t)(B0 + grow0) * S_LEN + t0) * HDIM + ghid;
  float* hout1 = Hout + ((size_t)(B0 + grow1) * S_LEN + t0) * HDIM + ghid;

  h16x8 xg_c = *(const h16x8*)xgp;

  for (int tt = 0; tt < TCHr; ++tt) {
    const h16x8 xgh = xg_c;
    const _Float16* xgn = xgp + (size_t)BATCH * G4;
    if (tt + 1 < TCHr) xg_c = *(const h16x8*)xgn;

    f32x4 acc0 = {0.f, 0.f, 0.f, 0.f}, acc1 = {0.f, 0.f, 0.f, 0.f};
    #pragma unroll
    for (int ks = 0; ks < 4; ++ks) {
      const int by = (lr * 256 + ks * 64 + lk * 16) ^ ((lr & 7) << 4);
      short8 ah = *(const short8*)((const char*)hA + by);
      acc0 = __builtin_amdgcn_mfma_f32_16x16x32_bf16(ah, bf[(ks << 1) | 0], acc0, 0, 0, 0);
      acc0 = __builtin_amdgcn_mfma_f32_16x16x32_bf16(ah, bf[(ks << 1) | 1], acc0, 0, 0, 0);
      acc1 = __builtin_amdgcn_mfma_f32_16x16x32_bf16(ah, bf[8 | (ks << 1) | 0], acc1, 0, 0, 0);
      acc1 = __builtin_amdgcn_mfma_f32_16x16x32_bf16(ah, bf[8 | (ks << 1) | 1], acc1, 0, 0, 0);
    }

    #pragma unroll
    for (int j = 0; j < 4; ++j) {
      int r16 = lk * 4 + j;
      int colA = w * 32 + lr;
      int byA = (r16 * 2048 + colA * 4) ^ ((r16 & 3) << 5);
      *(float*)((char*)pp + byA) = acc0[j] + (float)xgh[j];
      int colB = colA + 16;
      int byB = (r16 * 2048 + colB * 4) ^ ((r16 & 3) << 5);
      *(float*)((char*)pp + byB) = acc1[j] + (float)xgh[4 + j];
    }
    __syncthreads();

    {
      int b0 = grow0 * 2048, x0 = (grow0 & 3) << 5;
      float pi = *(const float*)((const char*)pp + ((b0 + (ghid)       * 4) ^ x0));
      float pf = *(const float*)((const char*)pp + ((b0 + (128 + ghid) * 4) ^ x0));
      float pg = *(const float*)((const char*)pp + ((b0 + (256 + ghid) * 4) ^ x0));
      float po = *(const float*)((const char*)pp + ((b0 + (384 + ghid) * 4) ^ x0));
      float gi = fsig(pi), gf = fsig(pf), gg = ftanh(pg), go = fsig(po);
      c0 = fmaf(gf, c0, gi * gg);
      float h0 = go * ftanh(c0);

      int b1 = grow1 * 2048, x1 = (grow1 & 3) << 5;
      float qi = *(const float*)((const char*)pp + ((b1 + (ghid)       * 4) ^ x1));
      float qf = *(const float*)((const char*)pp + ((b1 + (128 + ghid) * 4) ^ x1));
      float qg = *(const float*)((const char*)pp + ((b1 + (256 + ghid) * 4) ^ x1));
      float qo = *(const float*)((const char*)pp + ((b1 + (384 + ghid) * 4) ^ x1));
      float hi_ = fsig(qi), hf = fsig(qf), hg = ftanh(qg), ho = fsig(qo);
      c1 = fmaf(hf, c1, hi_ * hg);
      float h1 = ho * ftanh(c1);

      hout0[0] = h0;
      hout1[0] = h1;
      int by0 = (grow0 * 256 + ghid * 2) ^ ((grow0 & 7) << 4);
      int by1 = (grow1 * 256 + ghid * 2) ^ ((grow1 & 7) << 4);
      *(unsigned short*)((char*)hA + by0) = bf16_rne(h0);
      *(unsigned short*)((char*)hA + by1) = bf16_rne(h1);
    }
    __syncthreads();
    xgp = xgn;
    hout0 += HDIM;
    hout1 += HDIM;
  }
  cst[(B0 + grow0) * HDIM + ghid] = c0;
  cst[(B0 + grow1) * HDIM + ghid] = c1;
}

// ---------------------------------------------------------------------------
// Attention pass 1, MFMA (verified verbatim).
// ---------------------------------------------------------------------------
__global__ __launch_bounds__(256, 2)
void attn1_mfma(const float* __restrict__ Hs,
                const unsigned short* __restrict__ AWhi,
                const unsigned short* __restrict__ AWlo,
                const float* __restrict__ attn_b, const float* __restrict__ v_w,
                const float* __restrict__ v_b, float* __restrict__ logits)
{
  __shared__ unsigned short Ahi[64][136];
  __shared__ unsigned short Alo[64][136];
  __shared__ unsigned short Bhi[128][72];
  __shared__ unsigned short Blo[128][72];
  const int tid = threadIdx.x;
  const int rowBase = blockIdx.x * 64;

  #pragma unroll
  for (int it = 0; it < 4; ++it) {
    int idx = tid + it * 256;
    int rr  = idx >> 4;
    int kg  = (idx & 15) * 8;
    const float* ap = &Hs[(size_t)(rowBase + rr) * HDIM + kg];
    float4 v0 = *(const float4*)ap;
    float4 v1 = *(const float4*)(ap + 4);
    float xs[8] = {v0.x, v0.y, v0.z, v0.w, v1.x, v1.y, v1.z, v1.w};
    unsigned short h[8], l8[8];
    #pragma unroll
    for (int j = 0; j < 8; ++j) {
      h[j]  = bf16_rne(xs[j]);
      l8[j] = bf16_rne(xs[j] - bf16_to_f(h[j]));
    }
    *(short8*)&Ahi[rr][kg] = *(short8*)h;
    *(short8*)&Alo[rr][kg] = *(short8*)l8;
  }

  const int w    = tid >> 6;
  const int ln   = tid & 63;
  const int fr   = ln & 15;
  const int kgrp = (ln >> 4) * 8;

  f32x4 acc[8] = {};
  #pragma unroll
  for (int kh = 0; kh < 2; ++kh) {
    __syncthreads();
    #pragma unroll
    for (int it = 0; it < 4; ++it) {
      int idx = tid + it * 256;
      int cc  = idx >> 3;
      int kg  = (idx & 7) * 8;
      *(short8*)&Bhi[cc][kg] = *(const short8*)&AWhi[(size_t)cc * HDIM + kh * 64 + kg];
      *(short8*)&Blo[cc][kg] = *(const short8*)&AWlo[(size_t)cc * HDIM + kh * 64 + kg];
    }
    __syncthreads();
    #pragma unroll
    for (int ks = 0; ks < 2; ++ks) {
      const int k0 = kh * 64 + ks * 32 + kgrp;
      const int kb = ks * 32 + kgrp;
      short8 ah = *(const short8*)&Ahi[(w << 4) + fr][k0];
      short8 al = *(const short8*)&Alo[(w << 4) + fr][k0];
      #pragma unroll
      for (int nt = 0; nt < 8; ++nt) {
        short8 bh = *(const short8*)&Bhi[nt * 16 + fr][kb];
        short8 bl = *(const short8*)&Blo[nt * 16 + fr][kb];
        acc[nt] = __builtin_amdgcn_mfma_f32_16x16x32_bf16(ah, bh, acc[nt], 0, 0, 0);
        acc[nt] = __builtin_amdgcn_mfma_f32_16x16x32_bf16(ah, bl, acc[nt], 0, 0, 0);
        acc[nt] = __builtin_amdgcn_mfma_f32_16x16x32_bf16(al, bh, acc[nt], 0, 0, 0);
      }
    }
  }

  float parts[4] = {0.f, 0.f, 0.f, 0.f};
  #pragma unroll
  for (int nt = 0; nt < 8; ++nt) {
    const int col = nt * 16 + fr;
    const float ab = attn_b[col];
    const float vw = v_w[col];
    #pragma unroll
    for (int j = 0; j < 4; ++j)
      parts[j] = fmaf(ftanh(acc[nt][j] + ab), vw, parts[j]);
  }
  #pragma unroll
  for (int j = 0; j < 4; ++j) {
    #pragma unroll
    for (int off = 1; off < 16; off <<= 1)
      parts[j] += __shfl_xor(parts[j], off);
  }
  if (fr == 0) {
    const float vb = v_b[0];
    #pragma unroll
    for (int j = 0; j < 4; ++j)
      logits[rowBase + (w << 4) + ((ln >> 4) << 2) + j] = parts[j] + vb;
  }
}

// ---------------------------------------------------------------------------
// Attention pass 2 (verified verbatim).
// ---------------------------------------------------------------------------
__global__ __launch_bounds__(128)
void attn2(const float* __restrict__ Hs, const float* __restrict__ logits,
           const float* __restrict__ fc_w, const float* __restrict__ fc_b,
           float* __restrict__ outp)
{
  const int b   = blockIdx.x;
  const int tid = threadIdx.x;
  __shared__ float pbuf[S_LEN];
  __shared__ float red[4];
  __shared__ float ctx_s[HDIM];
  float l0 = logits[b * S_LEN + tid];
  float l1 = logits[b * S_LEN + 128 + tid];
  float l2 = logits[b * S_LEN + 256 + tid];
  float l3 = logits[b * S_LEN + 384 + tid];
  float m = fmaxf(fmaxf(l0, l1), fmaxf(l2, l3));
  #pragma unroll
  for (int off = 1; off < 64; off <<= 1) m = fmaxf(m, __shfl_xor(m, off));
  if ((tid & 63) == 0) red[tid >> 6] = m;
  __syncthreads();
  m = fmaxf(red[0], red[1]);
  float p0 = __expf(l0 - m), p1 = __expf(l1 - m), p2 = __expf(l2 - m), p3 = __expf(l3 - m);
  pbuf[tid] = p0; pbuf[tid + 128] = p1; pbuf[tid + 256] = p2; pbuf[tid + 384] = p3;
  float sum = (p0 + p1) + (p2 + p3);
  #pragma unroll
  for (int off = 1; off < 64; off <<= 1) sum += __shfl_xor(sum, off);
  if ((tid & 63) == 0) red[2 + (tid >> 6)] = sum;
  __syncthreads();
  const float sinv = 1.0f / (red[2] + red[3]);
  float acc = 0.f;
  const float* hp = Hs + (size_t)b * S_LEN * HDIM + tid;
  #pragma unroll 4
  for (int t = 0; t < S_LEN; ++t) acc = fmaf(pbuf[t], hp[(size_t)t * HDIM], acc);
  ctx_s[tid] = acc * sinv;
  __syncthreads();
  if (tid < 7) {
    float a = fc_b[tid];
    const float* fw = fc_w + tid * HDIM;
    #pragma unroll 8
    for (int k = 0; k < HDIM; ++k) a = fmaf(ctx_s[k], fw[k], a);
    outp[b * 7 + tid] = a;
  }
}

// ---------------------------------------------------------------------------
extern "C" void kernel_launch(void* const* d_in, const int* in_sizes, int n_in,
                              void* d_out, int out_size, void* d_ws, size_t ws_size,
                              hipStream_t stream)
{
  const float* x      = (const float*)d_in[0];
  const float* w_ih0  = (const float*)d_in[1];
  const float* w_ih   = (const float*)d_in[2];
  const float* w_hh   = (const float*)d_in[3];
  const float* b_ih   = (const float*)d_in[4];
  const float* b_hh   = (const float*)d_in[5];
  const float* attn_w = (const float*)d_in[6];
  const float* attn_b = (const float*)d_in[7];
  const float* v_w    = (const float*)d_in[8];
  const float* v_b    = (const float*)d_in[9];
  const float* fc_w   = (const float*)d_in[10];
  const float* fc_b   = (const float*)d_in[11];
  float* outp = (float*)d_out;

  const size_t szH_b  = (size_t)BATCH * S_LEN * HDIM * 4;
  const int    nWih   = (NLAYER - 1) * G4 * HDIM;
  const size_t nWF    = (size_t)NLAYER * 16 * 16 * 64 * 8;
  const int    nAW    = HDIM * HDIM;
  const int    nW0    = 512 * 32;
  const size_t fixed  = 2 * szH_b + (size_t)NLAYER * BATCH * HDIM * 4
                      + (size_t)nWih * 2 * 2 + nWF * 2 + (size_t)nAW * 2 * 2
                      + (size_t)nW0 * 2 * 2
                      + (size_t)BATCH * S_LEN * 4;

  int tchShift = -1;
  for (int sh = 6; sh >= 3; --sh) {
    size_t ringBytes = (size_t)RING * (((size_t)BATCH * G4) << sh) * 2;
    if (ws_size >= fixed + ringBytes) { tchShift = sh; break; }
  }
  if (tchShift < 0) return;
  const int TCHr = 1 << tchShift;
  const int NCHr = S_LEN >> tchShift;

  char* p = (char*)d_ws;
  _Float16* XGring = (_Float16*)p;
  p += (size_t)RING * (((size_t)BATCH * G4) << tchShift) * 2;
  float* H0  = (float*)p; p += szH_b;
  float* H1  = (float*)p; p += szH_b;
  float* cst = (float*)p; p += (size_t)NLAYER * BATCH * HDIM * 4;
  float* lg  = (float*)p; p += (size_t)BATCH * S_LEN * 4;
  unsigned short* Whi  = (unsigned short*)p; p += (size_t)nWih * 2;
  unsigned short* Wlo  = (unsigned short*)p; p += (size_t)nWih * 2;
  unsigned short* WF   = (unsigned short*)p; p += nWF * 2;
  unsigned short* AWhi = (unsigned short*)p; p += (size_t)nAW * 2;
  unsigned short* AWlo = (unsigned short*)p; p += (size_t)nAW * 2;
  unsigned short* W0hi = (unsigned short*)p; p += (size_t)nW0 * 2;
  unsigned short* W0lo = (unsigned short*)p; p += (size_t)nW0 * 2;

  split_w<<<(nWih + 255) / 256, 256, 0, stream>>>(w_ih, Whi, Wlo, nWih);
  split_w<<<(nAW + 255) / 256, 256, 0, stream>>>(attn_w, AWhi, AWlo, nAW);
  w0_prep<<<(nW0 + 255) / 256, 256, 0, stream>>>(w_ih0, W0hi, W0lo);
  whh_prep<<<(NLAYER * 16 * 16 * 64 + 255) / 256, 256, 0, stream>>>(w_hh, WF);

  const int TG = TCHr / 4;
  for (int s = 0; s <= NLAYER + NCHr - 2; ++s) {
    int lmin = (s - (NCHr - 1) > 0) ? s - (NCHr - 1) : 0;
    int lmax = (s < NLAYER - 1) ? s : NLAYER - 1;
    int np   = lmax - lmin + 1;
    gemm_st<<<dim3(NBLK, TG, np), 1024, 0, stream>>>(
        x, H0, H1, W0hi, W0lo, Whi, Wlo, b_ih, b_hh, XGring, tchShift, s, lmin);
    scan_mfma<<<dim3(NBLK, np), 1024, 0, stream>>>(
        XGring, tchShift, WF, H0, H1, cst, s, lmin);
  }

  const float* Hlast = H1;  // layer 9 (odd) writes H1
  attn1_mfma<<<dim3(BATCH * S_LEN / 64), 256, 0, stream>>>(
      Hlast, AWhi, AWlo, attn_b, v_w, v_b, lg);
  attn2<<<BATCH, 128, 0, stream>>>(Hlast, lg, fc_w, fc_b, outp);
}

// Round 19
// 2013.723 us; speedup vs baseline: 1.3009x; 1.0674x over previous
//
#include <hip/hip_runtime.h>
#include <cstdint>
#include <cstddef>

#define S_LEN 512
#define HDIM  128
#define G4    512
#define BATCH 256
#define NLAYER 10
#define ROWS  16
#define NBLK  (BATCH / ROWS)  // 16
#define RING  10

typedef float f32x4 __attribute__((ext_vector_type(4)));
typedef short short8 __attribute__((ext_vector_type(8)));
typedef _Float16 h16x4 __attribute__((ext_vector_type(4)));
typedef _Float16 h16x8 __attribute__((ext_vector_type(8)));

__device__ __forceinline__ float fsig(float x) {
  return __builtin_amdgcn_rcpf(1.0f + __expf(-x));
}
__device__ __forceinline__ float ftanh(float x) {
  return fmaf(2.0f, __builtin_amdgcn_rcpf(1.0f + __expf(-2.0f * x)), -1.0f);
}
__device__ __forceinline__ unsigned short bf16_rne(float x) {
  unsigned int u = __float_as_uint(x);
  unsigned int r = (u + 0x7fffu + ((u >> 16) & 1u)) >> 16;
  return (unsigned short)r;
}
__device__ __forceinline__ float bf16_to_f(unsigned short h) {
  return __uint_as_float(((unsigned int)h) << 16);
}

// XGS layout per chunk slot (slot = c % RING), fp16:
//   elem at ((tt*16 + bi)*16 + w)*512 + ln*8 + ct*4 + j
//   = XG[b = bi*16 + (ln>>4)*4 + j][t = t0+tt][col = w*32 + ct*16 + (ln&15)]

// ---------------------------------------------------------------------------
__global__ void split_w(const float* __restrict__ W, unsigned short* __restrict__ hi,
                        unsigned short* __restrict__ lo, int n)
{
  int i = blockIdx.x * 256 + threadIdx.x;
  if (i < n) {
    float x = W[i];
    unsigned short h = bf16_rne(x);
    hi[i] = h;
    lo[i] = bf16_rne(x - bf16_to_f(h));
  }
}

// Pad w_ih0 [512][27] -> split bf16 [512][32] (zeros in k=27..31).
__global__ void w0_prep(const float* __restrict__ W, unsigned short* __restrict__ hi,
                        unsigned short* __restrict__ lo)
{
  int i = blockIdx.x * 256 + threadIdx.x;
  if (i >= 512 * 32) return;
  int col = i >> 5, k = i & 31;
  float v = (k < 27) ? W[col * 27 + k] : 0.f;
  unsigned short h = bf16_rne(v);
  hi[i] = h;
  lo[i] = bf16_rne(v - bf16_to_f(h));
}

// ---------------------------------------------------------------------------
// Pre-arrange split Whh into MFMA B-fragment-linear order (verified round 7).
// ---------------------------------------------------------------------------
__global__ __launch_bounds__(256)
void whh_prep(const float* __restrict__ Whh, unsigned short* __restrict__ WF)
{
  int idx = blockIdx.x * 256 + threadIdx.x;
  if (idx >= NLAYER * 16 * 16 * 64) return;
  int ln = idx & 63;
  int f  = (idx >> 6) & 15;
  int w  = (idx >> 10) & 15;
  int l  = idx >> 14;
  int ct = f >> 3, ks = (f >> 1) & 3, hl = f & 1;
  int col = w * 32 + ct * 16 + (ln & 15);
  int k0  = ks * 32 + (ln >> 4) * 8;
  const float* src = Whh + ((size_t)l * G4 + col) * HDIM + k0;
  unsigned short out[8];
  #pragma unroll
  for (int j = 0; j < 8; ++j) {
    float x = src[j];
    unsigned short h = bf16_rne(x);
    out[j] = hl ? bf16_rne(x - bf16_to_f(h)) : h;
  }
  *(short8*)&WF[(size_t)idx * 8] = *(short8*)out;
}

// ---------------------------------------------------------------------------
// Unified input-projection GEMM (layers 0..9), 1024 threads, 3D grid.
// A bf16 hi only (round-18 verified); NEW: A-fragments hoisted to registers
// once (by-invariant; compiler can't hoist LDS reads across barriers).
// Per-wave LDS reads: 96 -> 68.
// ---------------------------------------------------------------------------
__global__ __launch_bounds__(1024, 4)
void gemm_st(const float* __restrict__ x,
             const float* __restrict__ H0, const float* __restrict__ H1,
             const unsigned short* __restrict__ W0hi, const unsigned short* __restrict__ W0lo,
             const unsigned short* __restrict__ WhiAll, const unsigned short* __restrict__ WloAll,
             const float* __restrict__ bihAll, const float* __restrict__ bhhAll,
             _Float16* __restrict__ XGring, int tchShift, int s, int lmin)
{
  __shared__ unsigned short Ahi[4 * 16 * HDIM];   // 16KB, [tw] 4KB, swizzled
  __shared__ unsigned short Bhi[64 * HDIM];       // 16KB, swizzled
  __shared__ unsigned short Blo[64 * HDIM];

  const int l  = lmin + blockIdx.z;
  const int c  = s - l;
  const int bi = blockIdx.x;
  const int tg = blockIdx.y;
  const int tid = threadIdx.x;
  const int t0 = c << tchShift;
  const size_t slotF = ((size_t)BATCH * G4) << tchShift;
  _Float16* __restrict__ XG = XGring + (size_t)(c % RING) * slotF;
  const float* bih = bihAll + l * G4;
  const float* bhh = bhhAll + l * G4;

  // ---- stage A: 64 rows (16b x 4t) x K -> bf16 hi, swizzled ----
  {
    int row = tid >> 4;
    int tw = row >> 4, rr = row & 15;
    int ks16 = tid & 15;
    int b = bi * 16 + rr;
    int t = t0 + tg * 4 + tw;
    if (l == 0) {
      if (ks16 < 4) {
        int kg = ks16 * 8;
        const float* ap = &x[((size_t)b * S_LEN + t) * 27];
        unsigned short h8[8];
        #pragma unroll
        for (int j = 0; j < 8; ++j) {
          int k = kg + j;
          float v = (k < 27) ? ap[k] : 0.f;
          h8[j] = bf16_rne(v);
        }
        int byA = tw * 4096 + ((rr * 256 + kg * 2) ^ ((rr & 7) << 4));
        *(short8*)((char*)Ahi + byA) = *(short8*)h8;
      }
    } else {
      int kg = ks16 * 8;
      const float* Asrc = ((l - 1) & 1) ? H1 : H0;
      const float* ap = &Asrc[((size_t)b * S_LEN + t) * HDIM + kg];
      float4 v0 = *(const float4*)ap;
      float4 v1 = *(const float4*)(ap + 4);
      float xs[8] = {v0.x, v0.y, v0.z, v0.w, v1.x, v1.y, v1.z, v1.w};
      unsigned short h8[8];
      #pragma unroll
      for (int j = 0; j < 8; ++j) h8[j] = bf16_rne(xs[j]);
      int byA = tw * 4096 + ((rr * 256 + kg * 2) ^ ((rr & 7) << 4));
      *(short8*)((char*)Ahi + byA) = *(short8*)h8;
    }
  }
  __syncthreads();   // A visible

  const int ln = tid & 63, lr = ln & 15, lk = ln >> 4;
  const int w16 = tid >> 6;
  const int tw = w16 & 3, cg = w16 >> 2;
  const int tt = tg * 4 + tw;
  const unsigned short* Whi = WhiAll + (size_t)(l - 1) * G4 * HDIM;  // used only l>0
  const unsigned short* Wlo = WloAll + (size_t)(l - 1) * G4 * HDIM;

  // Hoist the by-invariant A fragments into registers (4 frags, 16 VGPRs).
  short8 ah[4];
  #pragma unroll
  for (int ks = 0; ks < 4; ++ks) {
    int fo = (lr * 256 + ks * 64 + lk * 16) ^ ((lr & 7) << 4);
    ah[ks] = *(const short8*)((char*)Ahi + tw * 4096 + fo);
  }
  #pragma unroll
  for (int ks = 0; ks < 4; ++ks) asm("" : "+v"(ah[ks]));

  for (int by = 0; by < 8; ++by) {
    if (l == 0) {
      if (tid < 256) {
        int cc = tid >> 2, kg = (tid & 3) * 8;
        int col = by * 64 + cc;
        int byB = (cc * 256 + kg * 2) ^ ((cc & 7) << 4);
        *(short8*)((char*)Bhi + byB) = *(const short8*)&W0hi[(size_t)col * 32 + kg];
        *(short8*)((char*)Blo + byB) = *(const short8*)&W0lo[(size_t)col * 32 + kg];
      }
    } else {
      int cc = tid >> 4, kg = (tid & 15) * 8;
      int col = by * 64 + cc;
      int byB = (cc * 256 + kg * 2) ^ ((cc & 7) << 4);
      *(short8*)((char*)Bhi + byB) = *(const short8*)&Whi[(size_t)col * HDIM + kg];
      *(short8*)((char*)Blo + byB) = *(const short8*)&Wlo[(size_t)col * HDIM + kg];
    }
    __syncthreads();   // B visible

    f32x4 acc = {0.f, 0.f, 0.f, 0.f};
    if (l == 0) {
      int fo = (lr * 256 + lk * 16) ^ ((lr & 7) << 4);
      short8 bh = *(const short8*)((char*)Bhi + cg * 4096 + fo);
      short8 bl = *(const short8*)((char*)Blo + cg * 4096 + fo);
      acc = __builtin_amdgcn_mfma_f32_16x16x32_bf16(ah[0], bh, acc, 0, 0, 0);
      acc = __builtin_amdgcn_mfma_f32_16x16x32_bf16(ah[0], bl, acc, 0, 0, 0);
    } else {
      #pragma unroll
      for (int ks = 0; ks < 4; ++ks) {
        int fo = (lr * 256 + ks * 64 + lk * 16) ^ ((lr & 7) << 4);
        short8 bh = *(const short8*)((char*)Bhi + cg * 4096 + fo);
        short8 bl = *(const short8*)((char*)Blo + cg * 4096 + fo);
        acc = __builtin_amdgcn_mfma_f32_16x16x32_bf16(ah[ks], bh, acc, 0, 0, 0);
        acc = __builtin_amdgcn_mfma_f32_16x16x32_bf16(ah[ks], bl, acc, 0, 0, 0);
      }
    }
    int col = by * 64 + cg * 16 + lr;
    float bs = bih[col] + bhh[col];
    h16x4 o;
    #pragma unroll
    for (int j = 0; j < 4; ++j) o[j] = (_Float16)(acc[j] + bs);
    size_t base = ((((size_t)tt * 16 + bi) * 16) + by * 2 + (cg >> 1)) << 9;
    *(h16x4*)(XG + base + ln * 8 + (cg & 1) * 4) = o;
    __syncthreads();   // B reads done before next restage
  }
}

// ---------------------------------------------------------------------------
// MFMA LSTM scan — round-17 verbatim (verified: bf16-h hi-only, 16 MFMAs,
// 4 hA b128 reads per wave-step).
// ---------------------------------------------------------------------------
__global__ __launch_bounds__(1024, 4)
void scan_mfma(const _Float16* __restrict__ XGring, int tchShift,
               const unsigned short* __restrict__ WF,
               float* __restrict__ H0, float* __restrict__ H1,
               float* __restrict__ cstAll, int s, int lmin)
{
  const int l  = lmin + blockIdx.y;
  const int ch = s - l;
  const int TCHr = 1 << tchShift;
  const int t0 = ch << tchShift;
  const _Float16* __restrict__ XG =
      XGring + (size_t)(ch % RING) * (((size_t)BATCH * G4) << tchShift);
  float* __restrict__ Hout = (l & 1) ? H1 : H0;
  float* __restrict__ cst  = cstAll + (size_t)l * BATCH * HDIM;
  const int B0  = blockIdx.x * ROWS;
  const int tid = threadIdx.x;
  const int w   = tid >> 6;
  const int ln  = tid & 63;
  const int lr  = ln & 15;
  const int lk  = ln >> 4;

  __shared__ unsigned short hA[ROWS * HDIM];      // 4KB, hi plane only, swizzled
  __shared__ float pp[ROWS * G4];                 // 32KB, pre-acts, swizzled

  short8 bf[16];
  {
    const unsigned short* wfp = WF + (((size_t)l * 16 + w) * 16) * 512 + (size_t)ln * 8;
    #pragma unroll
    for (int f = 0; f < 16; ++f) bf[f] = *(const short8*)(wfp + (size_t)f * 512);
    #pragma unroll
    for (int f = 0; f < 16; ++f) asm("" : "+v"(bf[f]));
  }

  const int grow0 = tid >> 7;
  const int grow1 = grow0 + 8;
  const int ghid  = tid & 127;
  float c0 = 0.f, c1 = 0.f;
  {
    float h0v = 0.f, h1v = 0.f;
    if (t0 > 0) {
      h0v = Hout[((size_t)(B0 + grow0) * S_LEN + (t0 - 1)) * HDIM + ghid];
      h1v = Hout[((size_t)(B0 + grow1) * S_LEN + (t0 - 1)) * HDIM + ghid];
      c0 = cst[(B0 + grow0) * HDIM + ghid];
      c1 = cst[(B0 + grow1) * HDIM + ghid];
    }
    int by0 = (grow0 * 256 + ghid * 2) ^ ((grow0 & 7) << 4);
    int by1 = (grow1 * 256 + ghid * 2) ^ ((grow1 & 7) << 4);
    *(unsigned short*)((char*)hA + by0) = bf16_rne(h0v);
    *(unsigned short*)((char*)hA + by1) = bf16_rne(h1v);
  }
  __syncthreads();

  const _Float16* xgp = XG + (((size_t)blockIdx.x * 16 + w) << 9) + (ln << 3);
  float* hout0 = Hout + ((size_t)(B0 + grow0) * S_LEN + t0) * HDIM + ghid;
  float* hout1 = Hout + ((size_t)(B0 + grow1) * S_LEN + t0) * HDIM + ghid;

  h16x8 xg_c = *(const h16x8*)xgp;

  for (int tt = 0; tt < TCHr; ++tt) {
    const h16x8 xgh = xg_c;
    const _Float16* xgn = xgp + (size_t)BATCH * G4;
    if (tt + 1 < TCHr) xg_c = *(const h16x8*)xgn;

    f32x4 acc0 = {0.f, 0.f, 0.f, 0.f}, acc1 = {0.f, 0.f, 0.f, 0.f};
    #pragma unroll
    for (int ks = 0; ks < 4; ++ks) {
      const int by = (lr * 256 + ks * 64 + lk * 16) ^ ((lr & 7) << 4);
      short8 ah = *(const short8*)((const char*)hA + by);
      acc0 = __builtin_amdgcn_mfma_f32_16x16x32_bf16(ah, bf[(ks << 1) | 0], acc0, 0, 0, 0);
      acc0 = __builtin_amdgcn_mfma_f32_16x16x32_bf16(ah, bf[(ks << 1) | 1], acc0, 0, 0, 0);
      acc1 = __builtin_amdgcn_mfma_f32_16x16x32_bf16(ah, bf[8 | (ks << 1) | 0], acc1, 0, 0, 0);
      acc1 = __builtin_amdgcn_mfma_f32_16x16x32_bf16(ah, bf[8 | (ks << 1) | 1], acc1, 0, 0, 0);
    }

    #pragma unroll
    for (int j = 0; j < 4; ++j) {
      int r16 = lk * 4 + j;
      int colA = w * 32 + lr;
      int byA = (r16 * 2048 + colA * 4) ^ ((r16 & 3) << 5);
      *(float*)((char*)pp + byA) = acc0[j] + (float)xgh[j];
      int colB = colA + 16;
      int byB = (r16 * 2048 + colB * 4) ^ ((r16 & 3) << 5);
      *(float*)((char*)pp + byB) = acc1[j] + (float)xgh[4 + j];
    }
    __syncthreads();

    {
      int b0 = grow0 * 2048, x0 = (grow0 & 3) << 5;
      float pi = *(const float*)((const char*)pp + ((b0 + (ghid)       * 4) ^ x0));
      float pf = *(const float*)((const char*)pp + ((b0 + (128 + ghid) * 4) ^ x0));
      float pg = *(const float*)((const char*)pp + ((b0 + (256 + ghid) * 4) ^ x0));
      float po = *(const float*)((const char*)pp + ((b0 + (384 + ghid) * 4) ^ x0));
      float gi = fsig(pi), gf = fsig(pf), gg = ftanh(pg), go = fsig(po);
      c0 = fmaf(gf, c0, gi * gg);
      float h0 = go * ftanh(c0);

      int b1 = grow1 * 2048, x1 = (grow1 & 3) << 5;
      float qi = *(const float*)((const char*)pp + ((b1 + (ghid)       * 4) ^ x1));
      float qf = *(const float*)((const char*)pp + ((b1 + (128 + ghid) * 4) ^ x1));
      float qg = *(const float*)((const char*)pp + ((b1 + (256 + ghid) * 4) ^ x1));
      float qo = *(const float*)((const char*)pp + ((b1 + (384 + ghid) * 4) ^ x1));
      float hi_ = fsig(qi), hf = fsig(qf), hg = ftanh(qg), ho = fsig(qo);
      c1 = fmaf(hf, c1, hi_ * hg);
      float h1 = ho * ftanh(c1);

      hout0[0] = h0;
      hout1[0] = h1;
      int by0 = (grow0 * 256 + ghid * 2) ^ ((grow0 & 7) << 4);
      int by1 = (grow1 * 256 + ghid * 2) ^ ((grow1 & 7) << 4);
      *(unsigned short*)((char*)hA + by0) = bf16_rne(h0);
      *(unsigned short*)((char*)hA + by1) = bf16_rne(h1);
    }
    __syncthreads();
    xgp = xgn;
    hout0 += HDIM;
    hout1 += HDIM;
  }
  cst[(B0 + grow0) * HDIM + ghid] = c0;
  cst[(B0 + grow1) * HDIM + ghid] = c1;
}

// ---------------------------------------------------------------------------
// Attention pass 1, MFMA (verified verbatim).
// ---------------------------------------------------------------------------
__global__ __launch_bounds__(256, 2)
void attn1_mfma(const float* __restrict__ Hs,
                const unsigned short* __restrict__ AWhi,
                const unsigned short* __restrict__ AWlo,
                const float* __restrict__ attn_b, const float* __restrict__ v_w,
                const float* __restrict__ v_b, float* __restrict__ logits)
{
  __shared__ unsigned short Ahi[64][136];
  __shared__ unsigned short Alo[64][136];
  __shared__ unsigned short Bhi[128][72];
  __shared__ unsigned short Blo[128][72];
  const int tid = threadIdx.x;
  const int rowBase = blockIdx.x * 64;

  #pragma unroll
  for (int it = 0; it < 4; ++it) {
    int idx = tid + it * 256;
    int rr  = idx >> 4;
    int kg  = (idx & 15) * 8;
    const float* ap = &Hs[(size_t)(rowBase + rr) * HDIM + kg];
    float4 v0 = *(const float4*)ap;
    float4 v1 = *(const float4*)(ap + 4);
    float xs[8] = {v0.x, v0.y, v0.z, v0.w, v1.x, v1.y, v1.z, v1.w};
    unsigned short h[8], l8[8];
    #pragma unroll
    for (int j = 0; j < 8; ++j) {
      h[j]  = bf16_rne(xs[j]);
      l8[j] = bf16_rne(xs[j] - bf16_to_f(h[j]));
    }
    *(short8*)&Ahi[rr][kg] = *(short8*)h;
    *(short8*)&Alo[rr][kg] = *(short8*)l8;
  }

  const int w    = tid >> 6;
  const int ln   = tid & 63;
  const int fr   = ln & 15;
  const int kgrp = (ln >> 4) * 8;

  f32x4 acc[8] = {};
  #pragma unroll
  for (int kh = 0; kh < 2; ++kh) {
    __syncthreads();
    #pragma unroll
    for (int it = 0; it < 4; ++it) {
      int idx = tid + it * 256;
      int cc  = idx >> 3;
      int kg  = (idx & 7) * 8;
      *(short8*)&Bhi[cc][kg] = *(const short8*)&AWhi[(size_t)cc * HDIM + kh * 64 + kg];
      *(short8*)&Blo[cc][kg] = *(const short8*)&AWlo[(size_t)cc * HDIM + kh * 64 + kg];
    }
    __syncthreads();
    #pragma unroll
    for (int ks = 0; ks < 2; ++ks) {
      const int k0 = kh * 64 + ks * 32 + kgrp;
      const int kb = ks * 32 + kgrp;
      short8 ah = *(const short8*)&Ahi[(w << 4) + fr][k0];
      short8 al = *(const short8*)&Alo[(w << 4) + fr][k0];
      #pragma unroll
      for (int nt = 0; nt < 8; ++nt) {
        short8 bh = *(const short8*)&Bhi[nt * 16 + fr][kb];
        short8 bl = *(const short8*)&Blo[nt * 16 + fr][kb];
        acc[nt] = __builtin_amdgcn_mfma_f32_16x16x32_bf16(ah, bh, acc[nt], 0, 0, 0);
        acc[nt] = __builtin_amdgcn_mfma_f32_16x16x32_bf16(ah, bl, acc[nt], 0, 0, 0);
        acc[nt] = __builtin_amdgcn_mfma_f32_16x16x32_bf16(al, bh, acc[nt], 0, 0, 0);
      }
    }
  }

  float parts[4] = {0.f, 0.f, 0.f, 0.f};
  #pragma unroll
  for (int nt = 0; nt < 8; ++nt) {
    const int col = nt * 16 + fr;
    const float ab = attn_b[col];
    const float vw = v_w[col];
    #pragma unroll
    for (int j = 0; j < 4; ++j)
      parts[j] = fmaf(ftanh(acc[nt][j] + ab), vw, parts[j]);
  }
  #pragma unroll
  for (int j = 0; j < 4; ++j) {
    #pragma unroll
    for (int off = 1; off < 16; off <<= 1)
      parts[j] += __shfl_xor(parts[j], off);
  }
  if (fr == 0) {
    const float vb = v_b[0];
    #pragma unroll
    for (int j = 0; j < 4; ++j)
      logits[rowBase + (w << 4) + ((ln >> 4) << 2) + j] = parts[j] + vb;
  }
}

// ---------------------------------------------------------------------------
// Attention pass 2 (verified verbatim).
// ---------------------------------------------------------------------------
__global__ __launch_bounds__(128)
void attn2(const float* __restrict__ Hs, const float* __restrict__ logits,
           const float* __restrict__ fc_w, const float* __restrict__ fc_b,
           float* __restrict__ outp)
{
  const int b   = blockIdx.x;
  const int tid = threadIdx.x;
  __shared__ float pbuf[S_LEN];
  __shared__ float red[4];
  __shared__ float ctx_s[HDIM];
  float l0 = logits[b * S_LEN + tid];
  float l1 = logits[b * S_LEN + 128 + tid];
  float l2 = logits[b * S_LEN + 256 + tid];
  float l3 = logits[b * S_LEN + 384 + tid];
  float m = fmaxf(fmaxf(l0, l1), fmaxf(l2, l3));
  #pragma unroll
  for (int off = 1; off < 64; off <<= 1) m = fmaxf(m, __shfl_xor(m, off));
  if ((tid & 63) == 0) red[tid >> 6] = m;
  __syncthreads();
  m = fmaxf(red[0], red[1]);
  float p0 = __expf(l0 - m), p1 = __expf(l1 - m), p2 = __expf(l2 - m), p3 = __expf(l3 - m);
  pbuf[tid] = p0; pbuf[tid + 128] = p1; pbuf[tid + 256] = p2; pbuf[tid + 384] = p3;
  float sum = (p0 + p1) + (p2 + p3);
  #pragma unroll
  for (int off = 1; off < 64; off <<= 1) sum += __shfl_xor(sum, off);
  if ((tid & 63) == 0) red[2 + (tid >> 6)] = sum;
  __syncthreads();
  const float sinv = 1.0f / (red[2] + red[3]);
  float acc = 0.f;
  const float* hp = Hs + (size_t)b * S_LEN * HDIM + tid;
  #pragma unroll 4
  for (int t = 0; t < S_LEN; ++t) acc = fmaf(pbuf[t], hp[(size_t)t * HDIM], acc);
  ctx_s[tid] = acc * sinv;
  __syncthreads();
  if (tid < 7) {
    float a = fc_b[tid];
    const float* fw = fc_w + tid * HDIM;
    #pragma unroll 8
    for (int k = 0; k < HDIM; ++k) a = fmaf(ctx_s[k], fw[k], a);
    outp[b * 7 + tid] = a;
  }
}

// ---------------------------------------------------------------------------
extern "C" void kernel_launch(void* const* d_in, const int* in_sizes, int n_in,
                              void* d_out, int out_size, void* d_ws, size_t ws_size,
                              hipStream_t stream)
{
  const float* x      = (const float*)d_in[0];
  const float* w_ih0  = (const float*)d_in[1];
  const float* w_ih   = (const float*)d_in[2];
  const float* w_hh   = (const float*)d_in[3];
  const float* b_ih   = (const float*)d_in[4];
  const float* b_hh   = (const float*)d_in[5];
  const float* attn_w = (const float*)d_in[6];
  const float* attn_b = (const float*)d_in[7];
  const float* v_w    = (const float*)d_in[8];
  const float* v_b    = (const float*)d_in[9];
  const float* fc_w   = (const float*)d_in[10];
  const float* fc_b   = (const float*)d_in[11];
  float* outp = (float*)d_out;

  const size_t szH_b  = (size_t)BATCH * S_LEN * HDIM * 4;
  const int    nWih   = (NLAYER - 1) * G4 * HDIM;
  const size_t nWF    = (size_t)NLAYER * 16 * 16 * 64 * 8;
  const int    nAW    = HDIM * HDIM;
  const int    nW0    = 512 * 32;
  const size_t fixed  = 2 * szH_b + (size_t)NLAYER * BATCH * HDIM * 4
                      + (size_t)nWih * 2 * 2 + nWF * 2 + (size_t)nAW * 2 * 2
                      + (size_t)nW0 * 2 * 2
                      + (size_t)BATCH * S_LEN * 4;

  int tchShift = -1;
  for (int sh = 6; sh >= 3; --sh) {
    size_t ringBytes = (size_t)RING * (((size_t)BATCH * G4) << sh) * 2;
    if (ws_size >= fixed + ringBytes) { tchShift = sh; break; }
  }
  if (tchShift < 0) return;
  const int TCHr = 1 << tchShift;
  const int NCHr = S_LEN >> tchShift;

  char* p = (char*)d_ws;
  _Float16* XGring = (_Float16*)p;
  p += (size_t)RING * (((size_t)BATCH * G4) << tchShift) * 2;
  float* H0  = (float*)p; p += szH_b;
  float* H1  = (float*)p; p += szH_b;
  float* cst = (float*)p; p += (size_t)NLAYER * BATCH * HDIM * 4;
  float* lg  = (float*)p; p += (size_t)BATCH * S_LEN * 4;
  unsigned short* Whi  = (unsigned short*)p; p += (size_t)nWih * 2;
  unsigned short* Wlo  = (unsigned short*)p; p += (size_t)nWih * 2;
  unsigned short* WF   = (unsigned short*)p; p += nWF * 2;
  unsigned short* AWhi = (unsigned short*)p; p += (size_t)nAW * 2;
  unsigned short* AWlo = (unsigned short*)p; p += (size_t)nAW * 2;
  unsigned short* W0hi = (unsigned short*)p; p += (size_t)nW0 * 2;
  unsigned short* W0lo = (unsigned short*)p; p += (size_t)nW0 * 2;

  split_w<<<(nWih + 255) / 256, 256, 0, stream>>>(w_ih, Whi, Wlo, nWih);
  split_w<<<(nAW + 255) / 256, 256, 0, stream>>>(attn_w, AWhi, AWlo, nAW);
  w0_prep<<<(nW0 + 255) / 256, 256, 0, stream>>>(w_ih0, W0hi, W0lo);
  whh_prep<<<(NLAYER * 16 * 16 * 64 + 255) / 256, 256, 0, stream>>>(w_hh, WF);

  const int TG = TCHr / 4;
  for (int s = 0; s <= NLAYER + NCHr - 2; ++s) {
    int lmin = (s - (NCHr - 1) > 0) ? s - (NCHr - 1) : 0;
    int lmax = (s < NLAYER - 1) ? s : NLAYER - 1;
    int np   = lmax - lmin + 1;
    gemm_st<<<dim3(NBLK, TG, np), 1024, 0, stream>>>(
        x, H0, H1, W0hi, W0lo, Whi, Wlo, b_ih, b_hh, XGring, tchShift, s, lmin);
    scan_mfma<<<dim3(NBLK, np), 1024, 0, stream>>>(
        XGring, tchShift, WF, H0, H1, cst, s, lmin);
  }

  const float* Hlast = H1;  // layer 9 (odd) writes H1
  attn1_mfma<<<dim3(BATCH * S_LEN / 64), 256, 0, stream>>>(
      Hlast, AWhi, AWlo, attn_b, v_w, v_b, lg);
  attn2<<<BATCH, 128, 0, stream>>>(Hlast, lg, fc_w, fc_b, outp);
}